// Round 3
// baseline (143.126 us; speedup 1.0000x reference)
//
#include <hip/hip_runtime.h>
#include <math.h>

#define BDIM 4
#define NDIM 4096
#define MDIM 4096
#define CDIM 128
#define KSEL 32
#define NGRID 4      // cells per dim
#define NCELL 64     // NGRID^3
#define CAP 128      // per-wave candidate cap (expected ~30 hits; P(>128) ~ 0)

typedef float v2f __attribute__((ext_vector_type(2)));

#define PRE_FLOATS (7 * CDIM)                       // folded weights: 896 floats
#define N_INTS (NCELL * BDIM * 2 + (NCELL + 1) * BDIM)  // counts + cursors + starts = 772
#define PTS4_OFF ((PRE_FLOATS + N_INTS) * 4)        // 6672 bytes, 16B aligned
#define WS_NEEDED (PTS4_OFF + (size_t)BDIM * MDIM * 16)

// ---------------------------------------------------------------------------
// Folded weights (fp64 accum, ~1e-7 abs err):
//   pre[0:3C)  = (Wq @ Wa) * log2e        pre[3C:6C) = (Wk @ Wa) * log2e
//   pre[6C:7C) = ((bq-bk) @ Wa + ba) * log2e
// log2e folded so softmax uses bare v_exp_f32 (exp2).
// ---------------------------------------------------------------------------
__global__ void precompute_kernel(const float* __restrict__ Wq, const float* __restrict__ bq,
                                  const float* __restrict__ Wk, const float* __restrict__ bk,
                                  const float* __restrict__ Wa, const float* __restrict__ ba,
                                  float* __restrict__ pre) {
    const double LOG2E = 1.4426950408889634074;
    const int c = threadIdx.x;   // 0..127
    const int r = blockIdx.x;    // 0..6
    if (r < 3) {
        double s = 0;
        for (int k = 0; k < CDIM; ++k) s += (double)Wq[r * CDIM + k] * (double)Wa[k * CDIM + c];
        pre[r * CDIM + c] = (float)(s * LOG2E);
    } else if (r < 6) {
        const int rr = r - 3;
        double s = 0;
        for (int k = 0; k < CDIM; ++k) s += (double)Wk[rr * CDIM + k] * (double)Wa[k * CDIM + c];
        pre[r * CDIM + c] = (float)(s * LOG2E);
    } else {
        double s = (double)ba[c];
        for (int k = 0; k < CDIM; ++k) s += ((double)bq[k] - (double)bk[k]) * (double)Wa[k * CDIM + c];
        pre[6 * CDIM + c] = (float)(s * LOG2E);
    }
}

__device__ __forceinline__ int cell_of(float v) {
    int c = (int)(v * 4.0f);
    return c < 0 ? 0 : (c > 3 ? 3 : c);
}

__global__ void zero_kernel(int* __restrict__ counts) {
    counts[blockIdx.x * 256 + threadIdx.x] = 0;   // zero counts[256]
}

__global__ void count_kernel(const float* __restrict__ nb, int* __restrict__ counts) {
    const int i = blockIdx.x * 256 + threadIdx.x;   // 0..16383
    const float x = nb[3 * i], y = nb[3 * i + 1], z = nb[3 * i + 2];
    const int b = i >> 12;
    atomicAdd(&counts[b * NCELL + (cell_of(z) * 4 + cell_of(y)) * 4 + cell_of(x)], 1);
}

__global__ void prefix_kernel(const int* __restrict__ counts, int* __restrict__ starts,
                              int* __restrict__ cursors) {
    const int b = threadIdx.x;
    if (b < BDIM) {
        int acc = 0;
        for (int c = 0; c < NCELL; ++c) {
            starts[b * (NCELL + 1) + c] = acc;
            cursors[b * NCELL + c] = acc;
            acc += counts[b * NCELL + c];
        }
        starts[b * (NCELL + 1) + NCELL] = acc;
    }
}

__global__ void scatter_kernel(const float* __restrict__ nb, int* __restrict__ cursors,
                               float4* __restrict__ pts4) {
    const int i = blockIdx.x * 256 + threadIdx.x;
    const float x = nb[3 * i], y = nb[3 * i + 1], z = nb[3 * i + 2];
    const int b = i >> 12, li = i & (MDIM - 1);
    const int cell = (cell_of(z) * 4 + cell_of(y)) * 4 + cell_of(x);
    const int slot = atomicAdd(&cursors[b * NCELL + cell], 1);
    pts4[(size_t)b * MDIM + slot] = make_float4(x, y, z, __int_as_float(li));
}

// ---------------------------------------------------------------------------
// Main kernel: 1 wave per anchor, 4 independent waves / 256-thread block.
// Phase 1: binned candidate scan (<=8 cells ~512 pts vs 4096), float4 loads
//          carrying (xyz, orig index). Exact-fp32 d2 test (no fma) matches ref.
// Selection: set semantics — first-K-by-index == K smallest indices. If >K
//          hits, 12-iter ballot binary-search on index threshold.
// Phase 2: packed-fp32 (v_pk_*) channel-pair softmax(exp2) + max-accumulate.
// ---------------------------------------------------------------------------
__launch_bounds__(256)
__global__ void attn2_kernel(const float* __restrict__ anchor,
                             const float* __restrict__ neighbor,
                             const float* __restrict__ Wd,
                             const float* __restrict__ bd,
                             const float* __restrict__ pre,
                             const float4* __restrict__ pts4,
                             const int* __restrict__ starts,
                             float* __restrict__ out) {
    __shared__ float4 cand[4][CAP];
    __shared__ float4 sel[4][KSEL];

    const int b    = blockIdx.x >> 10;
    const int n0   = (blockIdx.x & 1023) << 2;
    const int tid  = threadIdx.x;
    const int w    = tid >> 6;
    const int lane = tid & 63;

    const int n = n0 + w;
    const float* ap = anchor + ((size_t)b * NDIM + n) * 3;
    const float ax = ap[0], ay = ap[1], az = ap[2];
    const float* nbb = neighbor + (size_t)b * MDIM * 3;

    // per-lane channel-pair weights
    const v2f* pre2 = (const v2f*)pre;
    const v2f* wdp  = (const v2f*)Wd;
    const v2f* bdp  = (const v2f*)bd;
    const v2f wqa0 = pre2[0 * 64 + lane], wqa1 = pre2[1 * 64 + lane], wqa2 = pre2[2 * 64 + lane];
    const v2f wka0 = pre2[3 * 64 + lane], wka1 = pre2[4 * 64 + lane], wka2 = pre2[5 * 64 + lane];
    const v2f cav  = pre2[6 * 64 + lane];
    const v2f wd0 = wdp[0 * 64 + lane], wd1 = wdp[1 * 64 + lane], wd2 = wdp[2 * 64 + lane];
    const v2f bdv = bdp[lane];

    const v2f qa = ax * wqa0 + ay * wqa1 + az * wqa2 + cav;   // log2-domain
    const v2f ad = ax * wd0 + ay * wd1 + az * wd2 + bdv;

    // --- phase 1: binned candidate collection ---
    constexpr float R2 = (float)(0.12 * 0.12);
    const float RP = 0.1201f;  // widened for cell-range robustness; 2*RP < cell
    const unsigned long long lanelt = (1ull << lane) - 1ull;

    const int cx0 = max(0, (int)((ax - RP) * 4.0f)), cx1 = min(3, (int)((ax + RP) * 4.0f));
    const int cy0 = max(0, (int)((ay - RP) * 4.0f)), cy1 = min(3, (int)((ay + RP) * 4.0f));
    const int cz0 = max(0, (int)((az - RP) * 4.0f)), cz1 = min(3, (int)((az + RP) * 4.0f));

    const float4* pb = pts4 + (size_t)b * MDIM;
    const int* st = starts + b * (NCELL + 1);

    int cnt = 0;
    for (int cz = cz0; cz <= cz1; ++cz) {
        for (int cy = cy0; cy <= cy1; ++cy) {
            const int crow = (cz * 4 + cy) * 4;
            const int s = st[crow + cx0];
            const int e = st[crow + cx1 + 1];
            for (int base = s; base < e; base += 64) {
                const int i = base + lane;
                const bool valid = i < e;
                float4 p = make_float4(1e30f, 1e30f, 1e30f, 0.0f);
                if (valid) p = pb[i];
                // exact no-fma fp32: ((dx*dx + dy*dy) + dz*dz) — matches np ref
                const float dx = __fsub_rn(ax, p.x);
                const float dy = __fsub_rn(ay, p.y);
                const float dz = __fsub_rn(az, p.z);
                const float d2 = __fadd_rn(__fadd_rn(__fmul_rn(dx, dx), __fmul_rn(dy, dy)),
                                           __fmul_rn(dz, dz));
                const bool in = valid && (d2 < R2);
                const unsigned long long mk = __ballot(in);
                const int pos = cnt + __popcll(mk & lanelt);
                if (in && pos < CAP) cand[w][pos] = p;
                cnt += __popcll(mk);
            }
        }
    }

    // --- selection: the K smallest original indices among hits ---
    int eff;
    if (cnt == 0) {
        if (lane == 0) sel[w][0] = make_float4(nbb[0], nbb[1], nbb[2], __int_as_float(0));
        eff = 1;
    } else if (cnt <= KSEL) {
        if (lane < cnt) sel[w][lane] = cand[w][lane];
        eff = cnt;
    } else if (cnt <= CAP) {
        float4 c0v = make_float4(0, 0, 0, 0), c1v = make_float4(0, 0, 0, 0);
        int i0 = 0x7fffffff, i1 = 0x7fffffff;
        if (lane < cnt)      { c0v = cand[w][lane];      i0 = __float_as_int(c0v.w); }
        if (lane + 64 < cnt) { c1v = cand[w][lane + 64]; i1 = __float_as_int(c1v.w); }
        int lo = 0, hi = MDIM - 1;  // smallest T with count(idx<=T) >= KSEL (indices unique)
        while (lo < hi) {
            const int mid = (lo + hi) >> 1;
            const int c = __popcll(__ballot(i0 <= mid)) + __popcll(__ballot(i1 <= mid));
            if (c >= KSEL) hi = mid; else lo = mid + 1;
        }
        const bool k0 = (i0 <= lo);
        const unsigned long long m0 = __ballot(k0);
        if (k0) sel[w][__popcll(m0 & lanelt)] = c0v;
        const int cc0 = __popcll(m0);
        const bool k1 = (i1 <= lo);
        const unsigned long long m1 = __ballot(k1);
        if (k1) sel[w][cc0 + __popcll(m1 & lanelt)] = c1v;
        eff = KSEL;
    } else {
        // overflow fallback (statistically never): ordered full scan, first K
        int c2 = 0;
        for (int base = 0; base < MDIM && c2 < KSEL; base += 64) {
            const int m = base + lane;
            const float* p = nbb + 3 * m;
            const float nx = p[0], ny = p[1], nz = p[2];
            const float dx = __fsub_rn(ax, nx);
            const float dy = __fsub_rn(ay, ny);
            const float dz = __fsub_rn(az, nz);
            const float d2 = __fadd_rn(__fadd_rn(__fmul_rn(dx, dx), __fmul_rn(dy, dy)),
                                       __fmul_rn(dz, dz));
            const bool in = d2 < R2;
            const unsigned long long mk = __ballot(in);
            const int pos = c2 + __popcll(mk & lanelt);
            if (in && pos < KSEL) sel[w][pos] = make_float4(nx, ny, nz, 0.0f);
            c2 += __popcll(mk);
        }
        eff = KSEL;
    }

    const int eff4 = (eff + 3) & ~3;  // pad with a selected point: idempotent under max
    __builtin_amdgcn_wave_barrier();
    __builtin_amdgcn_s_waitcnt(0);    // LDS writes visible within wave
    if (lane >= eff && lane < eff4) {
        const float4 f = sel[w][0];
        sel[w][lane] = f;
    }
    __builtin_amdgcn_wave_barrier();

    // --- phase 2: packed channel softmax (exp2 domain) + max-accumulate ---
    v2f acc = { -1e30f, -1e30f };
    for (int j = 0; j < eff4; j += 4) {
        v2f ev[4], pr[4];
        float sv[4];
        #pragma unroll
        for (int t = 0; t < 4; ++t) {
            const float4 v = sel[w][j + t];
            const v2f l = qa - (v.x * wka0 + v.y * wka1 + v.z * wka2);
            v2f e; e.x = exp2f(l.x); e.y = exp2f(l.y);
            ev[t] = e;
            sv[t] = e.x + e.y;
            const v2f d = ad - (v.x * wd0 + v.y * wd1 + v.z * wd2);
            pr[t] = d * e;
        }
        #pragma unroll
        for (int off = 32; off >= 1; off >>= 1) {
            #pragma unroll
            for (int t = 0; t < 4; ++t) sv[t] += __shfl_xor(sv[t], off);
        }
        #pragma unroll
        for (int t = 0; t < 4; ++t) {
            const float inv = __builtin_amdgcn_rcpf(sv[t]);
            const v2f c = pr[t] * inv;
            acc.x = fmaxf(acc.x, c.x);
            acc.y = fmaxf(acc.y, c.y);
        }
    }

    float2 o; o.x = acc.x; o.y = acc.y;
    ((float2*)out)[((size_t)b * NDIM + n) * 64 + lane] = o;
}

// ---------------------------------------------------------------------------
// Fallback (ws too small for bins): R2-style full-scan kernel, interleaved.
// ---------------------------------------------------------------------------
__launch_bounds__(256)
__global__ void attn_fallback(const float* __restrict__ anchor,
                              const float* __restrict__ neighbor,
                              const float* __restrict__ Wd,
                              const float* __restrict__ bd,
                              const float* __restrict__ pre,
                              float* __restrict__ out) {
    __shared__ int    lists[4][KSEL];
    __shared__ float4 nxyz[4][KSEL];

    const int b = blockIdx.x >> 10, n0 = (blockIdx.x & 1023) << 2;
    const int tid = threadIdx.x, w = tid >> 6, lane = tid & 63;
    const int n = n0 + w;
    const float* ap = anchor + ((size_t)b * NDIM + n) * 3;
    const float ax = ap[0], ay = ap[1], az = ap[2];
    const float* nbb = neighbor + (size_t)b * MDIM * 3;

    const v2f* pre2 = (const v2f*)pre;
    const v2f* wdp = (const v2f*)Wd;
    const v2f* bdp = (const v2f*)bd;
    const v2f wqa0 = pre2[0 * 64 + lane], wqa1 = pre2[1 * 64 + lane], wqa2 = pre2[2 * 64 + lane];
    const v2f wka0 = pre2[3 * 64 + lane], wka1 = pre2[4 * 64 + lane], wka2 = pre2[5 * 64 + lane];
    const v2f cav = pre2[6 * 64 + lane];
    const v2f wd0 = wdp[0 * 64 + lane], wd1 = wdp[1 * 64 + lane], wd2 = wdp[2 * 64 + lane];
    const v2f bdv = bdp[lane];
    const v2f qa = ax * wqa0 + ay * wqa1 + az * wqa2 + cav;
    const v2f ad = ax * wd0 + ay * wd1 + az * wd2 + bdv;

    constexpr float R2 = (float)(0.12 * 0.12);
    const unsigned long long lanelt = (1ull << lane) - 1ull;
    int cnt = 0;
    for (int base = 0; base < MDIM && cnt < KSEL; base += 64) {
        const int m = base + lane;
        const float* p = nbb + 3 * m;
        const float dx = __fsub_rn(ax, p[0]);
        const float dy = __fsub_rn(ay, p[1]);
        const float dz = __fsub_rn(az, p[2]);
        const float d2 = __fadd_rn(__fadd_rn(__fmul_rn(dx, dx), __fmul_rn(dy, dy)),
                                   __fmul_rn(dz, dz));
        const bool in = d2 < R2;
        const unsigned long long mk = __ballot(in);
        const int pos = cnt + __popcll(mk & lanelt);
        if (in && pos < KSEL) lists[w][pos] = m;
        cnt += __popcll(mk);
    }
    int eff = cnt < KSEL ? cnt : KSEL;
    if (cnt == 0) { if (lane == 0) lists[w][0] = 0; eff = 1; }
    const int eff4 = (eff + 3) & ~3;
    if (lane == 0) for (int j = eff; j < eff4; ++j) lists[w][j] = lists[w][0];
    __builtin_amdgcn_wave_barrier();
    if (lane < eff4) {
        const float* p = nbb + 3 * lists[w][lane];
        nxyz[w][lane] = make_float4(p[0], p[1], p[2], 0.f);
    }
    __builtin_amdgcn_wave_barrier();

    v2f acc = { -1e30f, -1e30f };
    for (int j = 0; j < eff4; j += 4) {
        v2f ev[4], pr[4]; float sv[4];
        #pragma unroll
        for (int t = 0; t < 4; ++t) {
            const float4 v = nxyz[w][j + t];
            const v2f l = qa - (v.x * wka0 + v.y * wka1 + v.z * wka2);
            v2f e; e.x = exp2f(l.x); e.y = exp2f(l.y);
            ev[t] = e; sv[t] = e.x + e.y;
            const v2f d = ad - (v.x * wd0 + v.y * wd1 + v.z * wd2);
            pr[t] = d * e;
        }
        #pragma unroll
        for (int off = 32; off >= 1; off >>= 1) {
            #pragma unroll
            for (int t = 0; t < 4; ++t) sv[t] += __shfl_xor(sv[t], off);
        }
        #pragma unroll
        for (int t = 0; t < 4; ++t) {
            const float inv = __builtin_amdgcn_rcpf(sv[t]);
            const v2f c = pr[t] * inv;
            acc.x = fmaxf(acc.x, c.x);
            acc.y = fmaxf(acc.y, c.y);
        }
    }
    float2 o; o.x = acc.x; o.y = acc.y;
    ((float2*)out)[((size_t)b * NDIM + n) * 64 + lane] = o;
}

extern "C" void kernel_launch(void* const* d_in, const int* in_sizes, int n_in,
                              void* d_out, int out_size, void* d_ws, size_t ws_size,
                              hipStream_t stream) {
    const float* anchor   = (const float*)d_in[0];
    const float* neighbor = (const float*)d_in[1];
    const float* Wq = (const float*)d_in[2];
    const float* bq = (const float*)d_in[3];
    const float* Wk = (const float*)d_in[4];
    const float* bk = (const float*)d_in[5];
    const float* Wd = (const float*)d_in[6];
    const float* bd = (const float*)d_in[7];
    const float* Wa = (const float*)d_in[8];
    const float* ba = (const float*)d_in[9];
    float* out = (float*)d_out;

    float* pre = (float*)d_ws;
    int* ib = (int*)((char*)d_ws + PRE_FLOATS * 4);
    int* counts  = ib;
    int* cursors = ib + NCELL * BDIM;
    int* starts  = ib + NCELL * BDIM * 2;
    float4* pts4 = (float4*)((char*)d_ws + PTS4_OFF);

    precompute_kernel<<<dim3(7), dim3(CDIM), 0, stream>>>(Wq, bq, Wk, bk, Wa, ba, pre);

    if (ws_size >= WS_NEEDED) {
        zero_kernel<<<dim3(1), dim3(256), 0, stream>>>(counts);
        count_kernel<<<dim3(BDIM * MDIM / 256), dim3(256), 0, stream>>>(neighbor, counts);
        prefix_kernel<<<dim3(1), dim3(64), 0, stream>>>(counts, starts, cursors);
        scatter_kernel<<<dim3(BDIM * MDIM / 256), dim3(256), 0, stream>>>(neighbor, cursors, pts4);
        attn2_kernel<<<dim3(BDIM * NDIM / 4), dim3(256), 0, stream>>>(
            anchor, neighbor, Wd, bd, pre, pts4, starts, out);
    } else {
        attn_fallback<<<dim3(BDIM * NDIM / 4), dim3(256), 0, stream>>>(
            anchor, neighbor, Wd, bd, pre, out);
    }
}

// Round 4
// 124.548 us; speedup vs baseline: 1.1492x; 1.1492x over previous
//
#include <hip/hip_runtime.h>
#include <math.h>

#define BDIM 4
#define NDIM 4096
#define MDIM 4096
#define CDIM 128
#define KSEL 32
#define NCELL 64     // 4x4x4 grid, cell 0.25 >= 2*r widened => ball spans <=2 cells/dim
#define CAP 128      // per-wave candidate cap (expected ~30 hits; P(>128) ~ 0)

typedef float v2f __attribute__((ext_vector_type(2)));

// ws layout: pre[7*C] floats | starts[(NCELL+1)*BDIM] ints | pts4[B*M] float4
#define PRE_BYTES (7 * CDIM * 4)                       // 3584
#define STARTS_BYTES ((NCELL + 1) * BDIM * 4)          // 1040
#define PTS4_OFF (PRE_BYTES + STARTS_BYTES)            // 4624 (16B aligned)
#define WS_NEEDED (PTS4_OFF + (size_t)BDIM * MDIM * 16)

__device__ __forceinline__ int cell_of(float v) {
    int c = (int)(v * 4.0f);
    return c < 0 ? 0 : (c > 3 ? 3 : c);
}

// ---------------------------------------------------------------------------
// Fused setup: ONE kernel.
//   if do_bins: blocks 0..3 bin batch b (LDS counts -> wave-0 shuffle prefix
//     scan -> LDS-cursor scatter into pts4 = float4(x,y,z,orig_idx)); block 4
//     computes folded weights. else: single block computes folded weights only.
//   pre[0:3C)=(Wq@Wa)*log2e  pre[3C:6C)=(Wk@Wa)*log2e
//   pre[6C:7C)=((bq-bk)@Wa+ba)*log2e   (fp64 accum ~1e-7; exp -> v_exp_f32)
// ---------------------------------------------------------------------------
__launch_bounds__(1024)
__global__ void setup_kernel(const float* __restrict__ neighbor,
                             const float* __restrict__ Wq, const float* __restrict__ bq,
                             const float* __restrict__ Wk, const float* __restrict__ bk,
                             const float* __restrict__ Wa, const float* __restrict__ ba,
                             float* __restrict__ pre,
                             int* __restrict__ starts,
                             float4* __restrict__ pts4,
                             const int do_bins) {
    const int blk = blockIdx.x;
    const int t = threadIdx.x;
    if (do_bins && blk < BDIM) {
        __shared__ int cnts[NCELL];
        __shared__ int curs[NCELL];
        if (t < NCELL) cnts[t] = 0;
        __syncthreads();
        const float* nbb = neighbor + (size_t)blk * MDIM * 3;
        float px[4], py[4], pz[4];
        int cell[4];
        #pragma unroll
        for (int k = 0; k < 4; ++k) {
            const int i = t + k * 1024;
            const float x = nbb[3 * i], y = nbb[3 * i + 1], z = nbb[3 * i + 2];
            px[k] = x; py[k] = y; pz[k] = z;
            cell[k] = (cell_of(z) * 4 + cell_of(y)) * 4 + cell_of(x);
            atomicAdd(&cnts[cell[k]], 1);
        }
        __syncthreads();
        if (t < NCELL) {  // threads 0..63 == wave 0: shuffle exclusive scan
            const int v = cnts[t];
            int inc = v;
            #pragma unroll
            for (int off = 1; off < 64; off <<= 1) {
                const int u = __shfl_up(inc, off);
                if (t >= off) inc += u;
            }
            const int excl = inc - v;
            curs[t] = excl;
            starts[blk * (NCELL + 1) + t] = excl;
            if (t == NCELL - 1) starts[blk * (NCELL + 1) + NCELL] = inc;
        }
        __syncthreads();
        #pragma unroll
        for (int k = 0; k < 4; ++k) {
            const int i = t + k * 1024;
            const int slot = atomicAdd(&curs[cell[k]], 1);
            pts4[(size_t)blk * MDIM + slot] = make_float4(px[k], py[k], pz[k], __int_as_float(i));
        }
    } else if (!do_bins || blk == BDIM) {
        if (t < 7 * CDIM) {
            const double LOG2E = 1.4426950408889634074;
            const int r = t >> 7, c = t & (CDIM - 1);
            if (r < 3) {
                double s0 = 0, s1 = 0, s2 = 0, s3 = 0;
                for (int k = 0; k < CDIM; k += 4) {
                    s0 += (double)Wq[r * CDIM + k + 0] * (double)Wa[(k + 0) * CDIM + c];
                    s1 += (double)Wq[r * CDIM + k + 1] * (double)Wa[(k + 1) * CDIM + c];
                    s2 += (double)Wq[r * CDIM + k + 2] * (double)Wa[(k + 2) * CDIM + c];
                    s3 += (double)Wq[r * CDIM + k + 3] * (double)Wa[(k + 3) * CDIM + c];
                }
                pre[r * CDIM + c] = (float)(((s0 + s1) + (s2 + s3)) * LOG2E);
            } else if (r < 6) {
                const int rr = r - 3;
                double s0 = 0, s1 = 0, s2 = 0, s3 = 0;
                for (int k = 0; k < CDIM; k += 4) {
                    s0 += (double)Wk[rr * CDIM + k + 0] * (double)Wa[(k + 0) * CDIM + c];
                    s1 += (double)Wk[rr * CDIM + k + 1] * (double)Wa[(k + 1) * CDIM + c];
                    s2 += (double)Wk[rr * CDIM + k + 2] * (double)Wa[(k + 2) * CDIM + c];
                    s3 += (double)Wk[rr * CDIM + k + 3] * (double)Wa[(k + 3) * CDIM + c];
                }
                pre[r * CDIM + c] = (float)(((s0 + s1) + (s2 + s3)) * LOG2E);
            } else {
                double s = (double)ba[c];
                for (int k = 0; k < CDIM; ++k)
                    s += ((double)bq[k] - (double)bk[k]) * (double)Wa[k * CDIM + c];
                pre[6 * CDIM + c] = (float)(s * LOG2E);
            }
        }
    }
}

// ---------------------------------------------------------------------------
// Main kernel: 1 wave per anchor, 4 independent waves / 256-thread block.
// Phase 1: binned candidate scan (<=4 rows of <=2 contiguous cells; ~512 pts),
//          float4 loads carrying (xyz, orig index); exact no-fma fp32 d2 test.
// Selection: set semantics — first-K-by-index == K smallest indices; if >K
//          hits, 12-iter ballot binary-search on index threshold.
// Phase 2: packed-fp32 channel-pair softmax (exp2 domain) + max-accumulate.
// ---------------------------------------------------------------------------
__launch_bounds__(256)
__global__ void attn2_kernel(const float* __restrict__ anchor,
                             const float* __restrict__ neighbor,
                             const float* __restrict__ Wd,
                             const float* __restrict__ bd,
                             const float* __restrict__ pre,
                             const float4* __restrict__ pts4,
                             const int* __restrict__ starts,
                             float* __restrict__ out) {
    __shared__ float4 cand[4][CAP];
    __shared__ float4 sel[4][KSEL];

    const int b    = blockIdx.x >> 10;
    const int n0   = (blockIdx.x & 1023) << 2;
    const int tid  = threadIdx.x;
    const int w    = tid >> 6;
    const int lane = tid & 63;

    const int n = n0 + w;
    const float* ap = anchor + ((size_t)b * NDIM + n) * 3;
    const float ax = ap[0], ay = ap[1], az = ap[2];
    const float* nbb = neighbor + (size_t)b * MDIM * 3;

    // per-lane channel-pair weights
    const v2f* pre2 = (const v2f*)pre;
    const v2f* wdp  = (const v2f*)Wd;
    const v2f* bdp  = (const v2f*)bd;
    const v2f wqa0 = pre2[0 * 64 + lane], wqa1 = pre2[1 * 64 + lane], wqa2 = pre2[2 * 64 + lane];
    const v2f wka0 = pre2[3 * 64 + lane], wka1 = pre2[4 * 64 + lane], wka2 = pre2[5 * 64 + lane];
    const v2f cav  = pre2[6 * 64 + lane];
    const v2f wd0 = wdp[0 * 64 + lane], wd1 = wdp[1 * 64 + lane], wd2 = wdp[2 * 64 + lane];
    const v2f bdv = bdp[lane];

    const v2f qa = ax * wqa0 + ay * wqa1 + az * wqa2 + cav;   // log2-domain
    const v2f ad = ax * wd0 + ay * wd1 + az * wd2 + bdv;

    // --- phase 1: binned candidate collection ---
    constexpr float R2 = (float)(0.12 * 0.12);
    const float RP = 0.1201f;  // widened; 2*RP < 0.25 => <=2 cells/dim, always
    const unsigned long long lanelt = (1ull << lane) - 1ull;

    const int cx0 = max(0, (int)((ax - RP) * 4.0f)), cx1 = min(3, (int)((ax + RP) * 4.0f));
    const int cy0 = max(0, (int)((ay - RP) * 4.0f)), cy1 = min(3, (int)((ay + RP) * 4.0f));
    const int cz0 = max(0, (int)((az - RP) * 4.0f)), cz1 = min(3, (int)((az + RP) * 4.0f));

    const float4* pb = pts4 + (size_t)b * MDIM;
    const int* st = starts + b * (NCELL + 1);

    // hoist row ranges (<=4 rows) so their loads overlap
    int rs[4], re[4];
    int nr = 0;
    for (int cz = cz0; cz <= cz1; ++cz)
        for (int cy = cy0; cy <= cy1; ++cy) {
            const int crow = (cz * 4 + cy) * 4;
            rs[nr] = st[crow + cx0];
            re[nr] = st[crow + cx1 + 1];
            ++nr;
        }

    int cnt = 0;
    for (int r = 0; r < nr; ++r) {
        const int rend = re[r];
        for (int base = rs[r]; base < rend; base += 64) {
            const int i = base + lane;
            const bool valid = i < rend;
            float4 p = make_float4(1e30f, 1e30f, 1e30f, 0.0f);
            if (valid) p = pb[i];
            // exact no-fma fp32: ((dx*dx + dy*dy) + dz*dz) — matches np ref
            const float dx = __fsub_rn(ax, p.x);
            const float dy = __fsub_rn(ay, p.y);
            const float dz = __fsub_rn(az, p.z);
            const float d2 = __fadd_rn(__fadd_rn(__fmul_rn(dx, dx), __fmul_rn(dy, dy)),
                                       __fmul_rn(dz, dz));
            const bool in = valid && (d2 < R2);
            const unsigned long long mk = __ballot(in);
            const int pos = cnt + __popcll(mk & lanelt);
            if (in && pos < CAP) cand[w][pos] = p;
            cnt += __popcll(mk);
        }
    }

    // --- selection: the K smallest original indices among hits ---
    int eff;
    if (cnt == 0) {
        if (lane == 0) sel[w][0] = make_float4(nbb[0], nbb[1], nbb[2], __int_as_float(0));
        eff = 1;
    } else if (cnt <= KSEL) {
        if (lane < cnt) sel[w][lane] = cand[w][lane];
        eff = cnt;
    } else if (cnt <= CAP) {
        float4 c0v = make_float4(0, 0, 0, 0), c1v = make_float4(0, 0, 0, 0);
        int i0 = 0x7fffffff, i1 = 0x7fffffff;
        if (lane < cnt)      { c0v = cand[w][lane];      i0 = __float_as_int(c0v.w); }
        if (lane + 64 < cnt) { c1v = cand[w][lane + 64]; i1 = __float_as_int(c1v.w); }
        int lo = 0, hi = MDIM - 1;  // smallest T with count(idx<=T) >= KSEL (indices unique)
        while (lo < hi) {
            const int mid = (lo + hi) >> 1;
            const int c = __popcll(__ballot(i0 <= mid)) + __popcll(__ballot(i1 <= mid));
            if (c >= KSEL) hi = mid; else lo = mid + 1;
        }
        const bool k0 = (i0 <= lo);
        const unsigned long long m0 = __ballot(k0);
        if (k0) sel[w][__popcll(m0 & lanelt)] = c0v;
        const int cc0 = __popcll(m0);
        const bool k1 = (i1 <= lo);
        const unsigned long long m1 = __ballot(k1);
        if (k1) sel[w][cc0 + __popcll(m1 & lanelt)] = c1v;
        eff = KSEL;
    } else {
        // overflow fallback (statistically never): ordered full scan, first K
        int c2 = 0;
        for (int base = 0; base < MDIM && c2 < KSEL; base += 64) {
            const int m = base + lane;
            const float* p = nbb + 3 * m;
            const float nx = p[0], ny = p[1], nz = p[2];
            const float dx = __fsub_rn(ax, nx);
            const float dy = __fsub_rn(ay, ny);
            const float dz = __fsub_rn(az, nz);
            const float d2 = __fadd_rn(__fadd_rn(__fmul_rn(dx, dx), __fmul_rn(dy, dy)),
                                       __fmul_rn(dz, dz));
            const bool in = d2 < R2;
            const unsigned long long mk = __ballot(in);
            const int pos = c2 + __popcll(mk & lanelt);
            if (in && pos < KSEL) sel[w][pos] = make_float4(nx, ny, nz, 0.0f);
            c2 += __popcll(mk);
        }
        eff = KSEL;
    }

    const int eff4 = (eff + 3) & ~3;  // pad with a selected point: idempotent under max
    __builtin_amdgcn_wave_barrier();
    __builtin_amdgcn_s_waitcnt(0);    // wave's LDS writes visible
    if (lane >= eff && lane < eff4) {
        const float4 f = sel[w][0];
        sel[w][lane] = f;
    }
    __builtin_amdgcn_wave_barrier();

    // --- phase 2: packed channel softmax (exp2 domain) + max-accumulate ---
    v2f acc = { -1e30f, -1e30f };
    for (int j = 0; j < eff4; j += 4) {
        v2f pr[4];
        float sv[4];
        #pragma unroll
        for (int t = 0; t < 4; ++t) {
            const float4 v = sel[w][j + t];
            const v2f l = qa - (v.x * wka0 + v.y * wka1 + v.z * wka2);
            v2f e; e.x = exp2f(l.x); e.y = exp2f(l.y);
            sv[t] = e.x + e.y;
            const v2f d = ad - (v.x * wd0 + v.y * wd1 + v.z * wd2);
            pr[t] = d * e;
        }
        #pragma unroll
        for (int off = 32; off >= 1; off >>= 1) {
            #pragma unroll
            for (int t = 0; t < 4; ++t) sv[t] += __shfl_xor(sv[t], off);
        }
        #pragma unroll
        for (int t = 0; t < 4; ++t) {
            const float inv = __builtin_amdgcn_rcpf(sv[t]);
            const v2f c = pr[t] * inv;
            acc.x = fmaxf(acc.x, c.x);
            acc.y = fmaxf(acc.y, c.y);
        }
    }

    float2 o; o.x = acc.x; o.y = acc.y;
    ((float2*)out)[((size_t)b * NDIM + n) * 64 + lane] = o;
}

// ---------------------------------------------------------------------------
// Fallback (ws too small for bins): full-scan kernel (ordered early-exit).
// ---------------------------------------------------------------------------
__launch_bounds__(256)
__global__ void attn_fallback(const float* __restrict__ anchor,
                              const float* __restrict__ neighbor,
                              const float* __restrict__ Wd,
                              const float* __restrict__ bd,
                              const float* __restrict__ pre,
                              float* __restrict__ out) {
    __shared__ int    lists[4][KSEL];
    __shared__ float4 nxyz[4][KSEL];

    const int b = blockIdx.x >> 10, n0 = (blockIdx.x & 1023) << 2;
    const int tid = threadIdx.x, w = tid >> 6, lane = tid & 63;
    const int n = n0 + w;
    const float* ap = anchor + ((size_t)b * NDIM + n) * 3;
    const float ax = ap[0], ay = ap[1], az = ap[2];
    const float* nbb = neighbor + (size_t)b * MDIM * 3;

    const v2f* pre2 = (const v2f*)pre;
    const v2f* wdp = (const v2f*)Wd;
    const v2f* bdp = (const v2f*)bd;
    const v2f wqa0 = pre2[0 * 64 + lane], wqa1 = pre2[1 * 64 + lane], wqa2 = pre2[2 * 64 + lane];
    const v2f wka0 = pre2[3 * 64 + lane], wka1 = pre2[4 * 64 + lane], wka2 = pre2[5 * 64 + lane];
    const v2f cav = pre2[6 * 64 + lane];
    const v2f wd0 = wdp[0 * 64 + lane], wd1 = wdp[1 * 64 + lane], wd2 = wdp[2 * 64 + lane];
    const v2f bdv = bdp[lane];
    const v2f qa = ax * wqa0 + ay * wqa1 + az * wqa2 + cav;
    const v2f ad = ax * wd0 + ay * wd1 + az * wd2 + bdv;

    constexpr float R2 = (float)(0.12 * 0.12);
    const unsigned long long lanelt = (1ull << lane) - 1ull;
    int cnt = 0;
    for (int base = 0; base < MDIM && cnt < KSEL; base += 64) {
        const int m = base + lane;
        const float* p = nbb + 3 * m;
        const float dx = __fsub_rn(ax, p[0]);
        const float dy = __fsub_rn(ay, p[1]);
        const float dz = __fsub_rn(az, p[2]);
        const float d2 = __fadd_rn(__fadd_rn(__fmul_rn(dx, dx), __fmul_rn(dy, dy)),
                                   __fmul_rn(dz, dz));
        const bool in = d2 < R2;
        const unsigned long long mk = __ballot(in);
        const int pos = cnt + __popcll(mk & lanelt);
        if (in && pos < KSEL) lists[w][pos] = m;
        cnt += __popcll(mk);
    }
    int eff = cnt < KSEL ? cnt : KSEL;
    if (cnt == 0) { if (lane == 0) lists[w][0] = 0; eff = 1; }
    const int eff4 = (eff + 3) & ~3;
    if (lane == 0) for (int j = eff; j < eff4; ++j) lists[w][j] = lists[w][0];
    __builtin_amdgcn_wave_barrier();
    if (lane < eff4) {
        const float* p = nbb + 3 * lists[w][lane];
        nxyz[w][lane] = make_float4(p[0], p[1], p[2], 0.f);
    }
    __builtin_amdgcn_wave_barrier();

    v2f acc = { -1e30f, -1e30f };
    for (int j = 0; j < eff4; j += 4) {
        v2f pr[4]; float sv[4];
        #pragma unroll
        for (int t = 0; t < 4; ++t) {
            const float4 v = nxyz[w][j + t];
            const v2f l = qa - (v.x * wka0 + v.y * wka1 + v.z * wka2);
            v2f e; e.x = exp2f(l.x); e.y = exp2f(l.y);
            sv[t] = e.x + e.y;
            const v2f d = ad - (v.x * wd0 + v.y * wd1 + v.z * wd2);
            pr[t] = d * e;
        }
        #pragma unroll
        for (int off = 32; off >= 1; off >>= 1) {
            #pragma unroll
            for (int t = 0; t < 4; ++t) sv[t] += __shfl_xor(sv[t], off);
        }
        #pragma unroll
        for (int t = 0; t < 4; ++t) {
            const float inv = __builtin_amdgcn_rcpf(sv[t]);
            const v2f c = pr[t] * inv;
            acc.x = fmaxf(acc.x, c.x);
            acc.y = fmaxf(acc.y, c.y);
        }
    }
    float2 o; o.x = acc.x; o.y = acc.y;
    ((float2*)out)[((size_t)b * NDIM + n) * 64 + lane] = o;
}

extern "C" void kernel_launch(void* const* d_in, const int* in_sizes, int n_in,
                              void* d_out, int out_size, void* d_ws, size_t ws_size,
                              hipStream_t stream) {
    const float* anchor   = (const float*)d_in[0];
    const float* neighbor = (const float*)d_in[1];
    const float* Wq = (const float*)d_in[2];
    const float* bq = (const float*)d_in[3];
    const float* Wk = (const float*)d_in[4];
    const float* bk = (const float*)d_in[5];
    const float* Wd = (const float*)d_in[6];
    const float* bd = (const float*)d_in[7];
    const float* Wa = (const float*)d_in[8];
    const float* ba = (const float*)d_in[9];
    float* out = (float*)d_out;

    float* pre   = (float*)d_ws;
    int* starts  = (int*)((char*)d_ws + PRE_BYTES);
    float4* pts4 = (float4*)((char*)d_ws + PTS4_OFF);

    if (ws_size >= WS_NEEDED) {
        setup_kernel<<<dim3(BDIM + 1), dim3(1024), 0, stream>>>(
            neighbor, Wq, bq, Wk, bk, Wa, ba, pre, starts, pts4, 1);
        attn2_kernel<<<dim3(BDIM * NDIM / 4), dim3(256), 0, stream>>>(
            anchor, neighbor, Wd, bd, pre, pts4, starts, out);
    } else {
        setup_kernel<<<dim3(1), dim3(1024), 0, stream>>>(
            neighbor, Wq, bq, Wk, bk, Wa, ba, pre, starts, pts4, 0);
        attn_fallback<<<dim3(BDIM * NDIM / 4), dim3(256), 0, stream>>>(
            anchor, neighbor, Wd, bd, pre, out);
    }
}

// Round 5
// 124.323 us; speedup vs baseline: 1.1512x; 1.0018x over previous
//
#include <hip/hip_runtime.h>
#include <math.h>

#define BDIM 4
#define NDIM 4096
#define MDIM 4096
#define CDIM 128
#define KSEL 32
#define NCELL 64     // 4x4x4 grid, cell 0.25 >= 2*r widened => ball spans <=2 cells/dim
#define CAP 128      // per-wave candidate cap (expected ~30 hits; P(>128) ~ 0)

typedef float v2f __attribute__((ext_vector_type(2)));

// ws layout: pre[7*C] floats | starts[(NCELL+1)*BDIM] ints | pts4[B*M] float4
#define PRE_BYTES (7 * CDIM * 4)                       // 3584
#define STARTS_BYTES ((NCELL + 1) * BDIM * 4)          // 1040
#define PTS4_OFF (PRE_BYTES + STARTS_BYTES)            // 4624 (16B aligned)
#define WS_NEEDED (PTS4_OFF + (size_t)BDIM * MDIM * 16)

// ---------------------------------------------------------------------------
// DPP wave64 sum: stays entirely in the VALU pipe (2-cyc adds w/ DPP modifier)
// vs __shfl_xor's ds_bpermute (~100+ cyc LDS latency per level). Grand total
// materializes in lane 63; extract with v_readlane (wave-uniform).
// ---------------------------------------------------------------------------
template <int CTRL, int MASK>
__device__ __forceinline__ float dpp_add(float x) {
    const int r = __builtin_amdgcn_update_dpp(0, __float_as_int(x), CTRL, MASK, 0xF, true);
    return x + __int_as_float(r);
}
// levels: xor1, xor2, xor4, xor8 (row sums), then bcast15->rows{1,3},
// bcast31->rows{2,3}; lane 63 holds the 64-lane total.
#define DPP_QUAD_XOR1 0xB1   // quad_perm [1,0,3,2]
#define DPP_QUAD_XOR2 0x4E   // quad_perm [2,3,0,1]
#define DPP_ROW_HALF_MIRROR 0x141
#define DPP_ROW_MIRROR      0x140
#define DPP_ROW_BCAST15     0x142
#define DPP_ROW_BCAST31     0x143

__device__ __forceinline__ int cell_of(float v) {
    int c = (int)(v * 4.0f);
    return c < 0 ? 0 : (c > 3 ? 3 : c);
}

// ---------------------------------------------------------------------------
// Fused setup: ONE kernel.
//   if do_bins: blocks 0..3 bin batch b (LDS counts -> wave-0 shuffle prefix
//     scan -> LDS-cursor scatter into pts4 = float4(x,y,z,orig_idx)); block 4
//     computes folded weights. else: single block computes folded weights only.
//   pre[0:3C)=(Wq@Wa)*log2e  pre[3C:6C)=(Wk@Wa)*log2e
//   pre[6C:7C)=((bq-bk)@Wa+ba)*log2e   (fp64 accum ~1e-7; exp -> v_exp_f32)
// ---------------------------------------------------------------------------
__launch_bounds__(1024)
__global__ void setup_kernel(const float* __restrict__ neighbor,
                             const float* __restrict__ Wq, const float* __restrict__ bq,
                             const float* __restrict__ Wk, const float* __restrict__ bk,
                             const float* __restrict__ Wa, const float* __restrict__ ba,
                             float* __restrict__ pre,
                             int* __restrict__ starts,
                             float4* __restrict__ pts4,
                             const int do_bins) {
    const int blk = blockIdx.x;
    const int t = threadIdx.x;
    if (do_bins && blk < BDIM) {
        __shared__ int cnts[NCELL];
        __shared__ int curs[NCELL];
        if (t < NCELL) cnts[t] = 0;
        __syncthreads();
        const float* nbb = neighbor + (size_t)blk * MDIM * 3;
        float px[4], py[4], pz[4];
        int cell[4];
        #pragma unroll
        for (int k = 0; k < 4; ++k) {
            const int i = t + k * 1024;
            const float x = nbb[3 * i], y = nbb[3 * i + 1], z = nbb[3 * i + 2];
            px[k] = x; py[k] = y; pz[k] = z;
            cell[k] = (cell_of(z) * 4 + cell_of(y)) * 4 + cell_of(x);
            atomicAdd(&cnts[cell[k]], 1);
        }
        __syncthreads();
        if (t < NCELL) {  // threads 0..63 == wave 0: shuffle exclusive scan
            const int v = cnts[t];
            int inc = v;
            #pragma unroll
            for (int off = 1; off < 64; off <<= 1) {
                const int u = __shfl_up(inc, off);
                if (t >= off) inc += u;
            }
            const int excl = inc - v;
            curs[t] = excl;
            starts[blk * (NCELL + 1) + t] = excl;
            if (t == NCELL - 1) starts[blk * (NCELL + 1) + NCELL] = inc;
        }
        __syncthreads();
        #pragma unroll
        for (int k = 0; k < 4; ++k) {
            const int i = t + k * 1024;
            const int slot = atomicAdd(&curs[cell[k]], 1);
            pts4[(size_t)blk * MDIM + slot] = make_float4(px[k], py[k], pz[k], __int_as_float(i));
        }
    } else if (!do_bins || blk == BDIM) {
        if (t < 7 * CDIM) {
            const double LOG2E = 1.4426950408889634074;
            const int r = t >> 7, c = t & (CDIM - 1);
            if (r < 3) {
                double s0 = 0, s1 = 0, s2 = 0, s3 = 0;
                for (int k = 0; k < CDIM; k += 4) {
                    s0 += (double)Wq[r * CDIM + k + 0] * (double)Wa[(k + 0) * CDIM + c];
                    s1 += (double)Wq[r * CDIM + k + 1] * (double)Wa[(k + 1) * CDIM + c];
                    s2 += (double)Wq[r * CDIM + k + 2] * (double)Wa[(k + 2) * CDIM + c];
                    s3 += (double)Wq[r * CDIM + k + 3] * (double)Wa[(k + 3) * CDIM + c];
                }
                pre[r * CDIM + c] = (float)(((s0 + s1) + (s2 + s3)) * LOG2E);
            } else if (r < 6) {
                const int rr = r - 3;
                double s0 = 0, s1 = 0, s2 = 0, s3 = 0;
                for (int k = 0; k < CDIM; k += 4) {
                    s0 += (double)Wk[rr * CDIM + k + 0] * (double)Wa[(k + 0) * CDIM + c];
                    s1 += (double)Wk[rr * CDIM + k + 1] * (double)Wa[(k + 1) * CDIM + c];
                    s2 += (double)Wk[rr * CDIM + k + 2] * (double)Wa[(k + 2) * CDIM + c];
                    s3 += (double)Wk[rr * CDIM + k + 3] * (double)Wa[(k + 3) * CDIM + c];
                }
                pre[r * CDIM + c] = (float)(((s0 + s1) + (s2 + s3)) * LOG2E);
            } else {
                double s = (double)ba[c];
                for (int k = 0; k < CDIM; ++k)
                    s += ((double)bq[k] - (double)bk[k]) * (double)Wa[k * CDIM + c];
                pre[6 * CDIM + c] = (float)(s * LOG2E);
            }
        }
    }
}

// ---------------------------------------------------------------------------
// Main kernel: 1 wave per anchor, 4 independent waves / 256-thread block.
// Phase 1: binned candidate scan (<=4 rows of <=2 contiguous cells; ~512 pts),
//          float4 loads carrying (xyz, orig index); exact no-fma fp32 d2 test.
// Selection: set semantics — first-K-by-index == K smallest indices; if >K
//          hits, 12-iter ballot binary-search on index threshold.
// Phase 2: packed-fp32 channel-pair softmax (exp2 domain); denominator via
//          DPP VALU reduction (no ds_bpermute latency chains).
// ---------------------------------------------------------------------------
__launch_bounds__(256)
__global__ void attn2_kernel(const float* __restrict__ anchor,
                             const float* __restrict__ neighbor,
                             const float* __restrict__ Wd,
                             const float* __restrict__ bd,
                             const float* __restrict__ pre,
                             const float4* __restrict__ pts4,
                             const int* __restrict__ starts,
                             float* __restrict__ out) {
    __shared__ float4 cand[4][CAP];
    __shared__ float4 sel[4][KSEL];

    const int b    = blockIdx.x >> 10;
    const int n0   = (blockIdx.x & 1023) << 2;
    const int tid  = threadIdx.x;
    const int w    = tid >> 6;
    const int lane = tid & 63;

    const int n = n0 + w;
    const float* ap = anchor + ((size_t)b * NDIM + n) * 3;
    const float ax = ap[0], ay = ap[1], az = ap[2];
    const float* nbb = neighbor + (size_t)b * MDIM * 3;

    // per-lane channel-pair weights
    const v2f* pre2 = (const v2f*)pre;
    const v2f* wdp  = (const v2f*)Wd;
    const v2f* bdp  = (const v2f*)bd;
    const v2f wqa0 = pre2[0 * 64 + lane], wqa1 = pre2[1 * 64 + lane], wqa2 = pre2[2 * 64 + lane];
    const v2f wka0 = pre2[3 * 64 + lane], wka1 = pre2[4 * 64 + lane], wka2 = pre2[5 * 64 + lane];
    const v2f cav  = pre2[6 * 64 + lane];
    const v2f wd0 = wdp[0 * 64 + lane], wd1 = wdp[1 * 64 + lane], wd2 = wdp[2 * 64 + lane];
    const v2f bdv = bdp[lane];

    const v2f qa = ax * wqa0 + ay * wqa1 + az * wqa2 + cav;   // log2-domain
    const v2f ad = ax * wd0 + ay * wd1 + az * wd2 + bdv;

    // --- phase 1: binned candidate collection ---
    constexpr float R2 = (float)(0.12 * 0.12);
    const float RP = 0.1201f;  // widened; 2*RP < 0.25 => <=2 cells/dim, always
    const unsigned long long lanelt = (1ull << lane) - 1ull;

    const int cx0 = max(0, (int)((ax - RP) * 4.0f)), cx1 = min(3, (int)((ax + RP) * 4.0f));
    const int cy0 = max(0, (int)((ay - RP) * 4.0f)), cy1 = min(3, (int)((ay + RP) * 4.0f));
    const int cz0 = max(0, (int)((az - RP) * 4.0f)), cz1 = min(3, (int)((az + RP) * 4.0f));

    const float4* pb = pts4 + (size_t)b * MDIM;
    const int* st = starts + b * (NCELL + 1);

    // hoist row ranges (<=4 rows) so their loads overlap
    int rs[4], re[4];
    int nr = 0;
    for (int cz = cz0; cz <= cz1; ++cz)
        for (int cy = cy0; cy <= cy1; ++cy) {
            const int crow = (cz * 4 + cy) * 4;
            rs[nr] = st[crow + cx0];
            re[nr] = st[crow + cx1 + 1];
            ++nr;
        }

    int cnt = 0;
    for (int r = 0; r < nr; ++r) {
        const int rend = re[r];
        for (int base = rs[r]; base < rend; base += 64) {
            const int i = base + lane;
            const bool valid = i < rend;
            float4 p = make_float4(1e30f, 1e30f, 1e30f, 0.0f);
            if (valid) p = pb[i];
            // exact no-fma fp32: ((dx*dx + dy*dy) + dz*dz) — matches np ref
            const float dx = __fsub_rn(ax, p.x);
            const float dy = __fsub_rn(ay, p.y);
            const float dz = __fsub_rn(az, p.z);
            const float d2 = __fadd_rn(__fadd_rn(__fmul_rn(dx, dx), __fmul_rn(dy, dy)),
                                       __fmul_rn(dz, dz));
            const bool in = valid && (d2 < R2);
            const unsigned long long mk = __ballot(in);
            const int pos = cnt + __popcll(mk & lanelt);
            if (in && pos < CAP) cand[w][pos] = p;
            cnt += __popcll(mk);
        }
    }

    // --- selection: the K smallest original indices among hits ---
    int eff;
    if (cnt == 0) {
        if (lane == 0) sel[w][0] = make_float4(nbb[0], nbb[1], nbb[2], __int_as_float(0));
        eff = 1;
    } else if (cnt <= KSEL) {
        if (lane < cnt) sel[w][lane] = cand[w][lane];
        eff = cnt;
    } else if (cnt <= CAP) {
        float4 c0v = make_float4(0, 0, 0, 0), c1v = make_float4(0, 0, 0, 0);
        int i0 = 0x7fffffff, i1 = 0x7fffffff;
        if (lane < cnt)      { c0v = cand[w][lane];      i0 = __float_as_int(c0v.w); }
        if (lane + 64 < cnt) { c1v = cand[w][lane + 64]; i1 = __float_as_int(c1v.w); }
        int lo = 0, hi = MDIM - 1;  // smallest T with count(idx<=T) >= KSEL (indices unique)
        while (lo < hi) {
            const int mid = (lo + hi) >> 1;
            const int c = __popcll(__ballot(i0 <= mid)) + __popcll(__ballot(i1 <= mid));
            if (c >= KSEL) hi = mid; else lo = mid + 1;
        }
        const bool k0 = (i0 <= lo);
        const unsigned long long m0 = __ballot(k0);
        if (k0) sel[w][__popcll(m0 & lanelt)] = c0v;
        const int cc0 = __popcll(m0);
        const bool k1 = (i1 <= lo);
        const unsigned long long m1 = __ballot(k1);
        if (k1) sel[w][cc0 + __popcll(m1 & lanelt)] = c1v;
        eff = KSEL;
    } else {
        // overflow fallback (statistically never): ordered full scan, first K
        int c2 = 0;
        for (int base = 0; base < MDIM && c2 < KSEL; base += 64) {
            const int m = base + lane;
            const float* p = nbb + 3 * m;
            const float nx = p[0], ny = p[1], nz = p[2];
            const float dx = __fsub_rn(ax, nx);
            const float dy = __fsub_rn(ay, ny);
            const float dz = __fsub_rn(az, nz);
            const float d2 = __fadd_rn(__fadd_rn(__fmul_rn(dx, dx), __fmul_rn(dy, dy)),
                                       __fmul_rn(dz, dz));
            const bool in = d2 < R2;
            const unsigned long long mk = __ballot(in);
            const int pos = c2 + __popcll(mk & lanelt);
            if (in && pos < KSEL) sel[w][pos] = make_float4(nx, ny, nz, 0.0f);
            c2 += __popcll(mk);
        }
        eff = KSEL;
    }

    const int eff4 = (eff + 3) & ~3;  // pad with a selected point: idempotent under max
    __builtin_amdgcn_wave_barrier();
    __builtin_amdgcn_s_waitcnt(0);    // wave's LDS writes visible
    if (lane >= eff && lane < eff4) {
        const float4 f = sel[w][0];
        sel[w][lane] = f;
    }
    __builtin_amdgcn_wave_barrier();

    // --- phase 2: packed channel softmax (exp2 domain) + max-accumulate ---
    v2f acc = { -1e30f, -1e30f };
    for (int j = 0; j < eff4; j += 4) {
        v2f pr[4];
        float sv[4];
        #pragma unroll
        for (int t = 0; t < 4; ++t) {
            const float4 v = sel[w][j + t];
            const v2f l = qa - (v.x * wka0 + v.y * wka1 + v.z * wka2);
            v2f e; e.x = exp2f(l.x); e.y = exp2f(l.y);
            sv[t] = e.x + e.y;
            const v2f d = ad - (v.x * wd0 + v.y * wd1 + v.z * wd2);
            pr[t] = d * e;
        }
        // DPP wave64 sum, 4 chains interleaved (level-major), all-VALU
        #pragma unroll
        for (int t = 0; t < 4; ++t) sv[t] = dpp_add<DPP_QUAD_XOR1, 0xF>(sv[t]);
        #pragma unroll
        for (int t = 0; t < 4; ++t) sv[t] = dpp_add<DPP_QUAD_XOR2, 0xF>(sv[t]);
        #pragma unroll
        for (int t = 0; t < 4; ++t) sv[t] = dpp_add<DPP_ROW_HALF_MIRROR, 0xF>(sv[t]);
        #pragma unroll
        for (int t = 0; t < 4; ++t) sv[t] = dpp_add<DPP_ROW_MIRROR, 0xF>(sv[t]);
        #pragma unroll
        for (int t = 0; t < 4; ++t) sv[t] = dpp_add<DPP_ROW_BCAST15, 0xA>(sv[t]);
        #pragma unroll
        for (int t = 0; t < 4; ++t) sv[t] = dpp_add<DPP_ROW_BCAST31, 0xC>(sv[t]);
        #pragma unroll
        for (int t = 0; t < 4; ++t) {
            const float tot = __int_as_float(__builtin_amdgcn_readlane(__float_as_int(sv[t]), 63));
            const float inv = __builtin_amdgcn_rcpf(tot);
            const v2f c = pr[t] * inv;
            acc.x = fmaxf(acc.x, c.x);
            acc.y = fmaxf(acc.y, c.y);
        }
    }

    float2 o; o.x = acc.x; o.y = acc.y;
    ((float2*)out)[((size_t)b * NDIM + n) * 64 + lane] = o;
}

// ---------------------------------------------------------------------------
// Fallback (ws too small for bins): full-scan kernel (ordered early-exit).
// ---------------------------------------------------------------------------
__launch_bounds__(256)
__global__ void attn_fallback(const float* __restrict__ anchor,
                              const float* __restrict__ neighbor,
                              const float* __restrict__ Wd,
                              const float* __restrict__ bd,
                              const float* __restrict__ pre,
                              float* __restrict__ out) {
    __shared__ int    lists[4][KSEL];
    __shared__ float4 nxyz[4][KSEL];

    const int b = blockIdx.x >> 10, n0 = (blockIdx.x & 1023) << 2;
    const int tid = threadIdx.x, w = tid >> 6, lane = tid & 63;
    const int n = n0 + w;
    const float* ap = anchor + ((size_t)b * NDIM + n) * 3;
    const float ax = ap[0], ay = ap[1], az = ap[2];
    const float* nbb = neighbor + (size_t)b * MDIM * 3;

    const v2f* pre2 = (const v2f*)pre;
    const v2f* wdp = (const v2f*)Wd;
    const v2f* bdp = (const v2f*)bd;
    const v2f wqa0 = pre2[0 * 64 + lane], wqa1 = pre2[1 * 64 + lane], wqa2 = pre2[2 * 64 + lane];
    const v2f wka0 = pre2[3 * 64 + lane], wka1 = pre2[4 * 64 + lane], wka2 = pre2[5 * 64 + lane];
    const v2f cav = pre2[6 * 64 + lane];
    const v2f wd0 = wdp[0 * 64 + lane], wd1 = wdp[1 * 64 + lane], wd2 = wdp[2 * 64 + lane];
    const v2f bdv = bdp[lane];
    const v2f qa = ax * wqa0 + ay * wqa1 + az * wqa2 + cav;
    const v2f ad = ax * wd0 + ay * wd1 + az * wd2 + bdv;

    constexpr float R2 = (float)(0.12 * 0.12);
    const unsigned long long lanelt = (1ull << lane) - 1ull;
    int cnt = 0;
    for (int base = 0; base < MDIM && cnt < KSEL; base += 64) {
        const int m = base + lane;
        const float* p = nbb + 3 * m;
        const float dx = __fsub_rn(ax, p[0]);
        const float dy = __fsub_rn(ay, p[1]);
        const float dz = __fsub_rn(az, p[2]);
        const float d2 = __fadd_rn(__fadd_rn(__fmul_rn(dx, dx), __fmul_rn(dy, dy)),
                                   __fmul_rn(dz, dz));
        const bool in = d2 < R2;
        const unsigned long long mk = __ballot(in);
        const int pos = cnt + __popcll(mk & lanelt);
        if (in && pos < KSEL) lists[w][pos] = m;
        cnt += __popcll(mk);
    }
    int eff = cnt < KSEL ? cnt : KSEL;
    if (cnt == 0) { if (lane == 0) lists[w][0] = 0; eff = 1; }
    const int eff4 = (eff + 3) & ~3;
    if (lane == 0) for (int j = eff; j < eff4; ++j) lists[w][j] = lists[w][0];
    __builtin_amdgcn_wave_barrier();
    if (lane < eff4) {
        const float* p = nbb + 3 * lists[w][lane];
        nxyz[w][lane] = make_float4(p[0], p[1], p[2], 0.f);
    }
    __builtin_amdgcn_wave_barrier();

    v2f acc = { -1e30f, -1e30f };
    for (int j = 0; j < eff4; j += 4) {
        v2f pr[4]; float sv[4];
        #pragma unroll
        for (int t = 0; t < 4; ++t) {
            const float4 v = nxyz[w][j + t];
            const v2f l = qa - (v.x * wka0 + v.y * wka1 + v.z * wka2);
            v2f e; e.x = exp2f(l.x); e.y = exp2f(l.y);
            sv[t] = e.x + e.y;
            const v2f d = ad - (v.x * wd0 + v.y * wd1 + v.z * wd2);
            pr[t] = d * e;
        }
        #pragma unroll
        for (int t = 0; t < 4; ++t) sv[t] = dpp_add<DPP_QUAD_XOR1, 0xF>(sv[t]);
        #pragma unroll
        for (int t = 0; t < 4; ++t) sv[t] = dpp_add<DPP_QUAD_XOR2, 0xF>(sv[t]);
        #pragma unroll
        for (int t = 0; t < 4; ++t) sv[t] = dpp_add<DPP_ROW_HALF_MIRROR, 0xF>(sv[t]);
        #pragma unroll
        for (int t = 0; t < 4; ++t) sv[t] = dpp_add<DPP_ROW_MIRROR, 0xF>(sv[t]);
        #pragma unroll
        for (int t = 0; t < 4; ++t) sv[t] = dpp_add<DPP_ROW_BCAST15, 0xA>(sv[t]);
        #pragma unroll
        for (int t = 0; t < 4; ++t) sv[t] = dpp_add<DPP_ROW_BCAST31, 0xC>(sv[t]);
        #pragma unroll
        for (int t = 0; t < 4; ++t) {
            const float tot = __int_as_float(__builtin_amdgcn_readlane(__float_as_int(sv[t]), 63));
            const float inv = __builtin_amdgcn_rcpf(tot);
            const v2f c = pr[t] * inv;
            acc.x = fmaxf(acc.x, c.x);
            acc.y = fmaxf(acc.y, c.y);
        }
    }
    float2 o; o.x = acc.x; o.y = acc.y;
    ((float2*)out)[((size_t)b * NDIM + n) * 64 + lane] = o;
}

extern "C" void kernel_launch(void* const* d_in, const int* in_sizes, int n_in,
                              void* d_out, int out_size, void* d_ws, size_t ws_size,
                              hipStream_t stream) {
    const float* anchor   = (const float*)d_in[0];
    const float* neighbor = (const float*)d_in[1];
    const float* Wq = (const float*)d_in[2];
    const float* bq = (const float*)d_in[3];
    const float* Wk = (const float*)d_in[4];
    const float* bk = (const float*)d_in[5];
    const float* Wd = (const float*)d_in[6];
    const float* bd = (const float*)d_in[7];
    const float* Wa = (const float*)d_in[8];
    const float* ba = (const float*)d_in[9];
    float* out = (float*)d_out;

    float* pre   = (float*)d_ws;
    int* starts  = (int*)((char*)d_ws + PRE_BYTES);
    float4* pts4 = (float4*)((char*)d_ws + PTS4_OFF);

    if (ws_size >= WS_NEEDED) {
        setup_kernel<<<dim3(BDIM + 1), dim3(1024), 0, stream>>>(
            neighbor, Wq, bq, Wk, bk, Wa, ba, pre, starts, pts4, 1);
        attn2_kernel<<<dim3(BDIM * NDIM / 4), dim3(256), 0, stream>>>(
            anchor, neighbor, Wd, bd, pre, pts4, starts, out);
    } else {
        setup_kernel<<<dim3(1), dim3(1024), 0, stream>>>(
            neighbor, Wq, bq, Wk, bk, Wa, ba, pre, starts, pts4, 0);
        attn_fallback<<<dim3(BDIM * NDIM / 4), dim3(256), 0, stream>>>(
            anchor, neighbor, Wd, bd, pre, out);
    }
}

// Round 6
// 118.676 us; speedup vs baseline: 1.2060x; 1.0476x over previous
//
#include <hip/hip_runtime.h>
#include <math.h>

#define BDIM 4
#define NDIM 4096
#define MDIM 4096
#define CDIM 128
#define KSEL 32
#define NCELL 64     // 4x4x4 grid, cell 0.25 >= 2*r widened => ball spans <=2 cells/dim
#define CAP 128      // per-wave candidate cap (expected ~30 hits; P(>128) ~ 0)

typedef float v2f __attribute__((ext_vector_type(2)));

// ws layout: pre[7*C] floats | starts[(NCELL+1)*BDIM] ints | pts4[B*M] float4
#define PRE_BYTES (7 * CDIM * 4)                       // 3584
#define STARTS_BYTES ((NCELL + 1) * BDIM * 4)          // 1040
#define PTS4_OFF (PRE_BYTES + STARTS_BYTES)            // 4624 (16B aligned)
#define WS_NEEDED (PTS4_OFF + (size_t)BDIM * MDIM * 16)

// ---------------------------------------------------------------------------
// Bare hardware exp2 (v_exp_f32, ~1 ulp). exp2f() would call __ocml_exp2_f32
// (~15-20 instr: rint/poly/fixups) — measured as ~1000 hidden VALU instr/wave.
// Inputs here are bounded (|l| < ~60), so no range handling needed.
// ---------------------------------------------------------------------------
__device__ __forceinline__ float exp2_hw(float x) {
    float r;
    asm("v_exp_f32 %0, %1" : "=v"(r) : "v"(x));
    return r;
}

// ---------------------------------------------------------------------------
// DPP wave64 sum: stays entirely in the VALU pipe. Grand total materializes
// in lane 63; extract with v_readlane (wave-uniform).
// ---------------------------------------------------------------------------
template <int CTRL, int MASK>
__device__ __forceinline__ float dpp_add(float x) {
    const int r = __builtin_amdgcn_update_dpp(0, __float_as_int(x), CTRL, MASK, 0xF, true);
    return x + __int_as_float(r);
}
#define DPP_QUAD_XOR1 0xB1   // quad_perm [1,0,3,2]
#define DPP_QUAD_XOR2 0x4E   // quad_perm [2,3,0,1]
#define DPP_ROW_HALF_MIRROR 0x141
#define DPP_ROW_MIRROR      0x140
#define DPP_ROW_BCAST15     0x142
#define DPP_ROW_BCAST31     0x143

__device__ __forceinline__ int cell_of(float v) {
    int c = (int)(v * 4.0f);
    return c < 0 ? 0 : (c > 3 ? 3 : c);
}

// ---------------------------------------------------------------------------
// Fused setup: ONE kernel.
//   if do_bins: blocks 0..3 bin batch b (LDS counts -> wave-0 shuffle prefix
//     scan -> LDS-cursor scatter into pts4 = float4(x,y,z,orig_idx)); block 4
//     computes folded weights. else: single block computes folded weights only.
//   pre[0:3C)  =  (Wq@Wa)*log2e
//   pre[3C:6C) = -(Wk@Wa)*log2e          <-- NEGATED: enables fma chains
//   pre[6C:7C) = ((bq-bk)@Wa+ba)*log2e   (fp64 accum ~1e-7; exp -> v_exp_f32)
// ---------------------------------------------------------------------------
__launch_bounds__(1024)
__global__ void setup_kernel(const float* __restrict__ neighbor,
                             const float* __restrict__ Wq, const float* __restrict__ bq,
                             const float* __restrict__ Wk, const float* __restrict__ bk,
                             const float* __restrict__ Wa, const float* __restrict__ ba,
                             float* __restrict__ pre,
                             int* __restrict__ starts,
                             float4* __restrict__ pts4,
                             const int do_bins) {
    const int blk = blockIdx.x;
    const int t = threadIdx.x;
    if (do_bins && blk < BDIM) {
        __shared__ int cnts[NCELL];
        __shared__ int curs[NCELL];
        if (t < NCELL) cnts[t] = 0;
        __syncthreads();
        const float* nbb = neighbor + (size_t)blk * MDIM * 3;
        float px[4], py[4], pz[4];
        int cell[4];
        #pragma unroll
        for (int k = 0; k < 4; ++k) {
            const int i = t + k * 1024;
            const float x = nbb[3 * i], y = nbb[3 * i + 1], z = nbb[3 * i + 2];
            px[k] = x; py[k] = y; pz[k] = z;
            cell[k] = (cell_of(z) * 4 + cell_of(y)) * 4 + cell_of(x);
            atomicAdd(&cnts[cell[k]], 1);
        }
        __syncthreads();
        if (t < NCELL) {  // threads 0..63 == wave 0: shuffle exclusive scan
            const int v = cnts[t];
            int inc = v;
            #pragma unroll
            for (int off = 1; off < 64; off <<= 1) {
                const int u = __shfl_up(inc, off);
                if (t >= off) inc += u;
            }
            const int excl = inc - v;
            curs[t] = excl;
            starts[blk * (NCELL + 1) + t] = excl;
            if (t == NCELL - 1) starts[blk * (NCELL + 1) + NCELL] = inc;
        }
        __syncthreads();
        #pragma unroll
        for (int k = 0; k < 4; ++k) {
            const int i = t + k * 1024;
            const int slot = atomicAdd(&curs[cell[k]], 1);
            pts4[(size_t)blk * MDIM + slot] = make_float4(px[k], py[k], pz[k], __int_as_float(i));
        }
    } else if (!do_bins || blk == BDIM) {
        if (t < 7 * CDIM) {
            const double LOG2E = 1.4426950408889634074;
            const int r = t >> 7, c = t & (CDIM - 1);
            if (r < 3) {
                double s0 = 0, s1 = 0, s2 = 0, s3 = 0;
                for (int k = 0; k < CDIM; k += 4) {
                    s0 += (double)Wq[r * CDIM + k + 0] * (double)Wa[(k + 0) * CDIM + c];
                    s1 += (double)Wq[r * CDIM + k + 1] * (double)Wa[(k + 1) * CDIM + c];
                    s2 += (double)Wq[r * CDIM + k + 2] * (double)Wa[(k + 2) * CDIM + c];
                    s3 += (double)Wq[r * CDIM + k + 3] * (double)Wa[(k + 3) * CDIM + c];
                }
                pre[r * CDIM + c] = (float)(((s0 + s1) + (s2 + s3)) * LOG2E);
            } else if (r < 6) {
                const int rr = r - 3;
                double s0 = 0, s1 = 0, s2 = 0, s3 = 0;
                for (int k = 0; k < CDIM; k += 4) {
                    s0 += (double)Wk[rr * CDIM + k + 0] * (double)Wa[(k + 0) * CDIM + c];
                    s1 += (double)Wk[rr * CDIM + k + 1] * (double)Wa[(k + 1) * CDIM + c];
                    s2 += (double)Wk[rr * CDIM + k + 2] * (double)Wa[(k + 2) * CDIM + c];
                    s3 += (double)Wk[rr * CDIM + k + 3] * (double)Wa[(k + 3) * CDIM + c];
                }
                pre[r * CDIM + c] = (float)(((s0 + s1) + (s2 + s3)) * (-LOG2E));  // negated
            } else {
                double s = (double)ba[c];
                for (int k = 0; k < CDIM; ++k)
                    s += ((double)bq[k] - (double)bk[k]) * (double)Wa[k * CDIM + c];
                pre[6 * CDIM + c] = (float)(s * LOG2E);
            }
        }
    }
}

// ---------------------------------------------------------------------------
// Main kernel: 1 wave per anchor, 4 independent waves / 256-thread block.
// Phase 1: binned candidate scan (<=4 rows of <=2 contiguous cells; ~512 pts),
//          float4 loads carrying (xyz, orig index); exact no-fma fp32 d2 test.
// Selection: set semantics — first-K-by-index == K smallest indices; if >K
//          hits, 12-iter ballot binary-search on index threshold.
// Phase 2: per-channel fma chains (negated weights) + bare v_exp_f32;
//          denominator via DPP VALU reduction.
// ---------------------------------------------------------------------------
__launch_bounds__(256)
__global__ void attn2_kernel(const float* __restrict__ anchor,
                             const float* __restrict__ neighbor,
                             const float* __restrict__ Wd,
                             const float* __restrict__ bd,
                             const float* __restrict__ pre,
                             const float4* __restrict__ pts4,
                             const int* __restrict__ starts,
                             float* __restrict__ out) {
    __shared__ float4 cand[4][CAP];
    __shared__ float4 sel[4][KSEL];

    const int b    = blockIdx.x >> 10;
    const int n0   = (blockIdx.x & 1023) << 2;
    const int tid  = threadIdx.x;
    const int w    = tid >> 6;
    const int lane = tid & 63;

    const int n = n0 + w;
    const float* ap = anchor + ((size_t)b * NDIM + n) * 3;
    const float ax = ap[0], ay = ap[1], az = ap[2];
    const float* nbb = neighbor + (size_t)b * MDIM * 3;

    // per-lane channel-pair weights (2 channels per lane)
    const v2f* pre2 = (const v2f*)pre;
    const v2f* wdp  = (const v2f*)Wd;
    const v2f* bdp  = (const v2f*)bd;
    const v2f wqa0 = pre2[0 * 64 + lane], wqa1 = pre2[1 * 64 + lane], wqa2 = pre2[2 * 64 + lane];
    const v2f nka0 = pre2[3 * 64 + lane], nka1 = pre2[4 * 64 + lane], nka2 = pre2[5 * 64 + lane];
    const v2f cav  = pre2[6 * 64 + lane];
    const v2f wd0 = wdp[0 * 64 + lane], wd1 = wdp[1 * 64 + lane], wd2 = wdp[2 * 64 + lane];
    const v2f bdv = bdp[lane];

    // qa in log2 domain; nka rows are pre-negated
    const float qax = fmaf(ax, wqa0.x, fmaf(ay, wqa1.x, fmaf(az, wqa2.x, cav.x)));
    const float qay = fmaf(ax, wqa0.y, fmaf(ay, wqa1.y, fmaf(az, wqa2.y, cav.y)));
    const float adx = fmaf(ax, wd0.x, fmaf(ay, wd1.x, fmaf(az, wd2.x, bdv.x)));
    const float ady = fmaf(ax, wd0.y, fmaf(ay, wd1.y, fmaf(az, wd2.y, bdv.y)));
    const v2f nwd0 = -wd0, nwd1 = -wd1, nwd2 = -wd2;  // negate for fma chains

    // --- phase 1: binned candidate collection ---
    constexpr float R2 = (float)(0.12 * 0.12);
    const float RP = 0.1201f;  // widened; 2*RP < 0.25 => <=2 cells/dim, always
    const unsigned long long lanelt = (1ull << lane) - 1ull;

    const int cx0 = max(0, (int)((ax - RP) * 4.0f)), cx1 = min(3, (int)((ax + RP) * 4.0f));
    const int cy0 = max(0, (int)((ay - RP) * 4.0f)), cy1 = min(3, (int)((ay + RP) * 4.0f));
    const int cz0 = max(0, (int)((az - RP) * 4.0f)), cz1 = min(3, (int)((az + RP) * 4.0f));

    const float4* pb = pts4 + (size_t)b * MDIM;
    const int* st = starts + b * (NCELL + 1);

    // hoist row ranges (<=4 rows) so their loads overlap
    int rs[4], re[4];
    int nr = 0;
    for (int cz = cz0; cz <= cz1; ++cz)
        for (int cy = cy0; cy <= cy1; ++cy) {
            const int crow = (cz * 4 + cy) * 4;
            rs[nr] = st[crow + cx0];
            re[nr] = st[crow + cx1 + 1];
            ++nr;
        }

    int cnt = 0;
    for (int r = 0; r < nr; ++r) {
        const int rend = re[r];
        for (int base = rs[r]; base < rend; base += 64) {
            const int i = base + lane;
            const bool valid = i < rend;
            float4 p = make_float4(1e30f, 1e30f, 1e30f, 0.0f);
            if (valid) p = pb[i];
            // exact no-fma fp32: ((dx*dx + dy*dy) + dz*dz) — matches np ref
            const float dx = __fsub_rn(ax, p.x);
            const float dy = __fsub_rn(ay, p.y);
            const float dz = __fsub_rn(az, p.z);
            const float d2 = __fadd_rn(__fadd_rn(__fmul_rn(dx, dx), __fmul_rn(dy, dy)),
                                       __fmul_rn(dz, dz));
            const bool in = valid && (d2 < R2);
            const unsigned long long mk = __ballot(in);
            const int pos = cnt + __popcll(mk & lanelt);
            if (in && pos < CAP) cand[w][pos] = p;
            cnt += __popcll(mk);
        }
    }

    // --- selection: the K smallest original indices among hits ---
    int eff;
    if (cnt == 0) {
        if (lane == 0) sel[w][0] = make_float4(nbb[0], nbb[1], nbb[2], __int_as_float(0));
        eff = 1;
    } else if (cnt <= KSEL) {
        if (lane < cnt) sel[w][lane] = cand[w][lane];
        eff = cnt;
    } else if (cnt <= CAP) {
        float4 c0v = make_float4(0, 0, 0, 0), c1v = make_float4(0, 0, 0, 0);
        int i0 = 0x7fffffff, i1 = 0x7fffffff;
        if (lane < cnt)      { c0v = cand[w][lane];      i0 = __float_as_int(c0v.w); }
        if (lane + 64 < cnt) { c1v = cand[w][lane + 64]; i1 = __float_as_int(c1v.w); }
        int lo = 0, hi = MDIM - 1;  // smallest T with count(idx<=T) >= KSEL (indices unique)
        while (lo < hi) {
            const int mid = (lo + hi) >> 1;
            const int c = __popcll(__ballot(i0 <= mid)) + __popcll(__ballot(i1 <= mid));
            if (c >= KSEL) hi = mid; else lo = mid + 1;
        }
        const bool k0 = (i0 <= lo);
        const unsigned long long m0 = __ballot(k0);
        if (k0) sel[w][__popcll(m0 & lanelt)] = c0v;
        const int cc0 = __popcll(m0);
        const bool k1 = (i1 <= lo);
        const unsigned long long m1 = __ballot(k1);
        if (k1) sel[w][cc0 + __popcll(m1 & lanelt)] = c1v;
        eff = KSEL;
    } else {
        // overflow fallback (statistically never): ordered full scan, first K
        int c2 = 0;
        for (int base = 0; base < MDIM && c2 < KSEL; base += 64) {
            const int m = base + lane;
            const float* p = nbb + 3 * m;
            const float nx = p[0], ny = p[1], nz = p[2];
            const float dx = __fsub_rn(ax, nx);
            const float dy = __fsub_rn(ay, ny);
            const float dz = __fsub_rn(az, nz);
            const float d2 = __fadd_rn(__fadd_rn(__fmul_rn(dx, dx), __fmul_rn(dy, dy)),
                                       __fmul_rn(dz, dz));
            const bool in = d2 < R2;
            const unsigned long long mk = __ballot(in);
            const int pos = c2 + __popcll(mk & lanelt);
            if (in && pos < KSEL) sel[w][pos] = make_float4(nx, ny, nz, 0.0f);
            c2 += __popcll(mk);
        }
        eff = KSEL;
    }

    const int eff4 = (eff + 3) & ~3;  // pad with a selected point: idempotent under max
    __builtin_amdgcn_wave_barrier();
    __builtin_amdgcn_s_waitcnt(0);    // wave's LDS writes visible
    if (lane >= eff && lane < eff4) {
        const float4 f = sel[w][0];
        sel[w][lane] = f;
    }
    __builtin_amdgcn_wave_barrier();

    // --- phase 2: channel softmax (exp2 domain, hw exp) + max-accumulate ---
    float acc0 = -1e30f, acc1 = -1e30f;
    for (int j = 0; j < eff4; j += 4) {
        float p0[4], p1[4], sv[4];
        #pragma unroll
        for (int t = 0; t < 4; ++t) {
            const float4 v = sel[w][j + t];
            const float lx = fmaf(v.x, nka0.x, fmaf(v.y, nka1.x, fmaf(v.z, nka2.x, qax)));
            const float ly = fmaf(v.x, nka0.y, fmaf(v.y, nka1.y, fmaf(v.z, nka2.y, qay)));
            const float ex = exp2_hw(lx);
            const float ey = exp2_hw(ly);
            sv[t] = ex + ey;
            const float dx_ = fmaf(v.x, nwd0.x, fmaf(v.y, nwd1.x, fmaf(v.z, nwd2.x, adx)));
            const float dy_ = fmaf(v.x, nwd0.y, fmaf(v.y, nwd1.y, fmaf(v.z, nwd2.y, ady)));
            p0[t] = dx_ * ex;
            p1[t] = dy_ * ey;
        }
        // DPP wave64 sum, 4 chains interleaved (level-major), all-VALU
        #pragma unroll
        for (int t = 0; t < 4; ++t) sv[t] = dpp_add<DPP_QUAD_XOR1, 0xF>(sv[t]);
        #pragma unroll
        for (int t = 0; t < 4; ++t) sv[t] = dpp_add<DPP_QUAD_XOR2, 0xF>(sv[t]);
        #pragma unroll
        for (int t = 0; t < 4; ++t) sv[t] = dpp_add<DPP_ROW_HALF_MIRROR, 0xF>(sv[t]);
        #pragma unroll
        for (int t = 0; t < 4; ++t) sv[t] = dpp_add<DPP_ROW_MIRROR, 0xF>(sv[t]);
        #pragma unroll
        for (int t = 0; t < 4; ++t) sv[t] = dpp_add<DPP_ROW_BCAST15, 0xA>(sv[t]);
        #pragma unroll
        for (int t = 0; t < 4; ++t) sv[t] = dpp_add<DPP_ROW_BCAST31, 0xC>(sv[t]);
        #pragma unroll
        for (int t = 0; t < 4; ++t) {
            const float tot = __int_as_float(__builtin_amdgcn_readlane(__float_as_int(sv[t]), 63));
            const float inv = __builtin_amdgcn_rcpf(tot);
            acc0 = fmaxf(acc0, p0[t] * inv);
            acc1 = fmaxf(acc1, p1[t] * inv);
        }
    }

    float2 o; o.x = acc0; o.y = acc1;
    ((float2*)out)[((size_t)b * NDIM + n) * 64 + lane] = o;
}

// ---------------------------------------------------------------------------
// Fallback (ws too small for bins): full-scan kernel (ordered early-exit).
// ---------------------------------------------------------------------------
__launch_bounds__(256)
__global__ void attn_fallback(const float* __restrict__ anchor,
                              const float* __restrict__ neighbor,
                              const float* __restrict__ Wd,
                              const float* __restrict__ bd,
                              const float* __restrict__ pre,
                              float* __restrict__ out) {
    __shared__ int    lists[4][KSEL];
    __shared__ float4 nxyz[4][KSEL];

    const int b = blockIdx.x >> 10, n0 = (blockIdx.x & 1023) << 2;
    const int tid = threadIdx.x, w = tid >> 6, lane = tid & 63;
    const int n = n0 + w;
    const float* ap = anchor + ((size_t)b * NDIM + n) * 3;
    const float ax = ap[0], ay = ap[1], az = ap[2];
    const float* nbb = neighbor + (size_t)b * MDIM * 3;

    const v2f* pre2 = (const v2f*)pre;
    const v2f* wdp = (const v2f*)Wd;
    const v2f* bdp = (const v2f*)bd;
    const v2f wqa0 = pre2[0 * 64 + lane], wqa1 = pre2[1 * 64 + lane], wqa2 = pre2[2 * 64 + lane];
    const v2f nka0 = pre2[3 * 64 + lane], nka1 = pre2[4 * 64 + lane], nka2 = pre2[5 * 64 + lane];
    const v2f cav = pre2[6 * 64 + lane];
    const v2f wd0 = wdp[0 * 64 + lane], wd1 = wdp[1 * 64 + lane], wd2 = wdp[2 * 64 + lane];
    const v2f bdv = bdp[lane];
    const float qax = fmaf(ax, wqa0.x, fmaf(ay, wqa1.x, fmaf(az, wqa2.x, cav.x)));
    const float qay = fmaf(ax, wqa0.y, fmaf(ay, wqa1.y, fmaf(az, wqa2.y, cav.y)));
    const float adx = fmaf(ax, wd0.x, fmaf(ay, wd1.x, fmaf(az, wd2.x, bdv.x)));
    const float ady = fmaf(ax, wd0.y, fmaf(ay, wd1.y, fmaf(az, wd2.y, bdv.y)));
    const v2f nwd0 = -wd0, nwd1 = -wd1, nwd2 = -wd2;

    constexpr float R2 = (float)(0.12 * 0.12);
    const unsigned long long lanelt = (1ull << lane) - 1ull;
    int cnt = 0;
    for (int base = 0; base < MDIM && cnt < KSEL; base += 64) {
        const int m = base + lane;
        const float* p = nbb + 3 * m;
        const float dx = __fsub_rn(ax, p[0]);
        const float dy = __fsub_rn(ay, p[1]);
        const float dz = __fsub_rn(az, p[2]);
        const float d2 = __fadd_rn(__fadd_rn(__fmul_rn(dx, dx), __fmul_rn(dy, dy)),
                                   __fmul_rn(dz, dz));
        const bool in = d2 < R2;
        const unsigned long long mk = __ballot(in);
        const int pos = cnt + __popcll(mk & lanelt);
        if (in && pos < KSEL) lists[w][pos] = m;
        cnt += __popcll(mk);
    }
    int eff = cnt < KSEL ? cnt : KSEL;
    if (cnt == 0) { if (lane == 0) lists[w][0] = 0; eff = 1; }
    const int eff4 = (eff + 3) & ~3;
    if (lane == 0) for (int j = eff; j < eff4; ++j) lists[w][j] = lists[w][0];
    __builtin_amdgcn_wave_barrier();
    if (lane < eff4) {
        const float* p = nbb + 3 * lists[w][lane];
        nxyz[w][lane] = make_float4(p[0], p[1], p[2], 0.f);
    }
    __builtin_amdgcn_wave_barrier();

    float acc0 = -1e30f, acc1 = -1e30f;
    for (int j = 0; j < eff4; j += 4) {
        float p0[4], p1[4], sv[4];
        #pragma unroll
        for (int t = 0; t < 4; ++t) {
            const float4 v = nxyz[w][j + t];
            const float lx = fmaf(v.x, nka0.x, fmaf(v.y, nka1.x, fmaf(v.z, nka2.x, qax)));
            const float ly = fmaf(v.x, nka0.y, fmaf(v.y, nka1.y, fmaf(v.z, nka2.y, qay)));
            const float ex = exp2_hw(lx);
            const float ey = exp2_hw(ly);
            sv[t] = ex + ey;
            const float dx_ = fmaf(v.x, nwd0.x, fmaf(v.y, nwd1.x, fmaf(v.z, nwd2.x, adx)));
            const float dy_ = fmaf(v.x, nwd0.y, fmaf(v.y, nwd1.y, fmaf(v.z, nwd2.y, ady)));
            p0[t] = dx_ * ex;
            p1[t] = dy_ * ey;
        }
        #pragma unroll
        for (int t = 0; t < 4; ++t) sv[t] = dpp_add<DPP_QUAD_XOR1, 0xF>(sv[t]);
        #pragma unroll
        for (int t = 0; t < 4; ++t) sv[t] = dpp_add<DPP_QUAD_XOR2, 0xF>(sv[t]);
        #pragma unroll
        for (int t = 0; t < 4; ++t) sv[t] = dpp_add<DPP_ROW_HALF_MIRROR, 0xF>(sv[t]);
        #pragma unroll
        for (int t = 0; t < 4; ++t) sv[t] = dpp_add<DPP_ROW_MIRROR, 0xF>(sv[t]);
        #pragma unroll
        for (int t = 0; t < 4; ++t) sv[t] = dpp_add<DPP_ROW_BCAST15, 0xA>(sv[t]);
        #pragma unroll
        for (int t = 0; t < 4; ++t) sv[t] = dpp_add<DPP_ROW_BCAST31, 0xC>(sv[t]);
        #pragma unroll
        for (int t = 0; t < 4; ++t) {
            const float tot = __int_as_float(__builtin_amdgcn_readlane(__float_as_int(sv[t]), 63));
            const float inv = __builtin_amdgcn_rcpf(tot);
            acc0 = fmaxf(acc0, p0[t] * inv);
            acc1 = fmaxf(acc1, p1[t] * inv);
        }
    }
    float2 o; o.x = acc0; o.y = acc1;
    ((float2*)out)[((size_t)b * NDIM + n) * 64 + lane] = o;
}

extern "C" void kernel_launch(void* const* d_in, const int* in_sizes, int n_in,
                              void* d_out, int out_size, void* d_ws, size_t ws_size,
                              hipStream_t stream) {
    const float* anchor   = (const float*)d_in[0];
    const float* neighbor = (const float*)d_in[1];
    const float* Wq = (const float*)d_in[2];
    const float* bq = (const float*)d_in[3];
    const float* Wk = (const float*)d_in[4];
    const float* bk = (const float*)d_in[5];
    const float* Wd = (const float*)d_in[6];
    const float* bd = (const float*)d_in[7];
    const float* Wa = (const float*)d_in[8];
    const float* ba = (const float*)d_in[9];
    float* out = (float*)d_out;

    float* pre   = (float*)d_ws;
    int* starts  = (int*)((char*)d_ws + PRE_BYTES);
    float4* pts4 = (float4*)((char*)d_ws + PTS4_OFF);

    if (ws_size >= WS_NEEDED) {
        setup_kernel<<<dim3(BDIM + 1), dim3(1024), 0, stream>>>(
            neighbor, Wq, bq, Wk, bk, Wa, ba, pre, starts, pts4, 1);
        attn2_kernel<<<dim3(BDIM * NDIM / 4), dim3(256), 0, stream>>>(
            anchor, neighbor, Wd, bd, pre, pts4, starts, out);
    } else {
        setup_kernel<<<dim3(1), dim3(1024), 0, stream>>>(
            neighbor, Wq, bq, Wk, bk, Wa, ba, pre, starts, pts4, 0);
        attn_fallback<<<dim3(BDIM * NDIM / 4), dim3(256), 0, stream>>>(
            anchor, neighbor, Wd, bd, pre, out);
    }
}

// Round 7
// 117.610 us; speedup vs baseline: 1.2170x; 1.0091x over previous
//
#include <hip/hip_runtime.h>
#include <hip/hip_cooperative_groups.h>
#include <math.h>

namespace cg = cooperative_groups;

#define BDIM 4
#define NDIM 4096
#define MDIM 4096
#define CDIM 128
#define KSEL 32
#define NCELL 64     // 4x4x4 grid, cell 0.25 >= 2*r widened => ball spans <=2 cells/dim
#define CAP 128      // per-wave candidate cap (expected ~30 hits; P(>128) ~ 0)
#define GRID_COOP 2048   // 8 anchors/block; must be fully co-resident (8 blk/CU x 256 CU)

typedef float v2f __attribute__((ext_vector_type(2)));

// ws layout: pre[7*C] floats | starts[(NCELL+1)*BDIM] ints | pts4[B*M] float4
#define PRE_BYTES (7 * CDIM * 4)                       // 3584
#define STARTS_BYTES ((NCELL + 1) * BDIM * 4)          // 1040
#define PTS4_OFF (PRE_BYTES + STARTS_BYTES)            // 4624 (16B aligned)
#define WS_NEEDED (PTS4_OFF + (size_t)BDIM * MDIM * 16)

// ---------------------------------------------------------------------------
// helpers
// ---------------------------------------------------------------------------
__device__ __forceinline__ float exp2_hw(float x) {   // bare v_exp_f32 (~1 ulp)
    float r;
    asm("v_exp_f32 %0, %1" : "=v"(r) : "v"(x));
    return r;
}

template <int CTRL, int MASK>
__device__ __forceinline__ float dpp_add(float x) {   // VALU-pipe reduction step
    const int r = __builtin_amdgcn_update_dpp(0, __float_as_int(x), CTRL, MASK, 0xF, true);
    return x + __int_as_float(r);
}
#define DPP_QUAD_XOR1 0xB1
#define DPP_QUAD_XOR2 0x4E
#define DPP_ROW_HALF_MIRROR 0x141
#define DPP_ROW_MIRROR      0x140
#define DPP_ROW_BCAST15     0x142
#define DPP_ROW_BCAST31     0x143

// # set bits of mk in lanes strictly below this lane (v_mbcnt_lo+hi, 2 instr)
__device__ __forceinline__ int rank_before(unsigned long long mk) {
    return __builtin_amdgcn_mbcnt_hi((unsigned)(mk >> 32),
                                     __builtin_amdgcn_mbcnt_lo((unsigned)mk, 0));
}

__device__ __forceinline__ int cell_of(float v) {
    int c = (int)(v * 4.0f);
    return c < 0 ? 0 : (c > 3 ? 3 : c);
}

// per-lane channel-pair weights (2 channels per lane)
struct LaneW {
    v2f wqa0, wqa1, wqa2;   // (Wq@Wa)*log2e
    v2f nka0, nka1, nka2;   // -(Wk@Wa)*log2e  (pre-negated)
    v2f cav;                // ((bq-bk)@Wa+ba)*log2e
    v2f wd0, wd1, wd2, bdv; // raw Wd rows + bd
};

__device__ __forceinline__ void load_lane_weights(LaneW& P, const float* pre,
                                                  const float* Wd, const float* bd, int lane) {
    const v2f* pre2 = (const v2f*)pre;
    const v2f* wdp  = (const v2f*)Wd;
    const v2f* bdp  = (const v2f*)bd;
    P.wqa0 = pre2[0 * 64 + lane]; P.wqa1 = pre2[1 * 64 + lane]; P.wqa2 = pre2[2 * 64 + lane];
    P.nka0 = pre2[3 * 64 + lane]; P.nka1 = pre2[4 * 64 + lane]; P.nka2 = pre2[5 * 64 + lane];
    P.cav  = pre2[6 * 64 + lane];
    P.wd0 = wdp[0 * 64 + lane]; P.wd1 = wdp[1 * 64 + lane]; P.wd2 = wdp[2 * 64 + lane];
    P.bdv = bdp[lane];
}

// ---------------------------------------------------------------------------
// attn core for ONE anchor, executed by one wave.
// Phase 1: binned candidate scan; exact no-fma fp32 d2 test (matches np ref).
// Selection: set semantics — first-K-by-index == K smallest indices; if >K
//   hits, 12-iter ballot binary-search on the index threshold.
// Phase 2: fma-chain logits, bare v_exp_f32, DPP wave64 softmax denominator.
// ---------------------------------------------------------------------------
__device__ __forceinline__ float2 attn_core(int w, int lane,
                                            float ax, float ay, float az,
                                            const LaneW& P,
                                            const float* nbb,     // interleaved batch base
                                            const float4* pb,     // binned pts, batch base
                                            const int* st,        // starts, batch base
                                            float4 (*cand)[CAP], float4 (*sel)[KSEL]) {
    const float qax = fmaf(ax, P.wqa0.x, fmaf(ay, P.wqa1.x, fmaf(az, P.wqa2.x, P.cav.x)));
    const float qay = fmaf(ax, P.wqa0.y, fmaf(ay, P.wqa1.y, fmaf(az, P.wqa2.y, P.cav.y)));
    const float adx = fmaf(ax, P.wd0.x, fmaf(ay, P.wd1.x, fmaf(az, P.wd2.x, P.bdv.x)));
    const float ady = fmaf(ax, P.wd0.y, fmaf(ay, P.wd1.y, fmaf(az, P.wd2.y, P.bdv.y)));
    const v2f nwd0 = -P.wd0, nwd1 = -P.wd1, nwd2 = -P.wd2;

    constexpr float R2 = (float)(0.12 * 0.12);
    const float RP = 0.1201f;   // widened; 2*RP < 0.25 => <=2 cells/dim always

    const int cx0 = max(0, (int)((ax - RP) * 4.0f)), cx1 = min(3, (int)((ax + RP) * 4.0f));
    const int cy0 = max(0, (int)((ay - RP) * 4.0f)), cy1 = min(3, (int)((ay + RP) * 4.0f));
    const int cz0 = max(0, (int)((az - RP) * 4.0f)), cz1 = min(3, (int)((az + RP) * 4.0f));

    int rs[4], re[4];
    int nr = 0;
    for (int cz = cz0; cz <= cz1; ++cz)
        for (int cy = cy0; cy <= cy1; ++cy) {
            const int crow = (cz * 4 + cy) * 4;
            rs[nr] = st[crow + cx0];
            re[nr] = st[crow + cx1 + 1];
            ++nr;
        }

    int cnt = 0;
    for (int r = 0; r < nr; ++r) {
        const int rend = re[r];
        for (int base = rs[r]; base < rend; base += 64) {
            const int i = base + lane;
            const bool valid = i < rend;
            float4 p = make_float4(1e30f, 1e30f, 1e30f, 0.0f);
            if (valid) p = pb[i];
            const float dx = __fsub_rn(ax, p.x);
            const float dy = __fsub_rn(ay, p.y);
            const float dz = __fsub_rn(az, p.z);
            const float d2 = __fadd_rn(__fadd_rn(__fmul_rn(dx, dx), __fmul_rn(dy, dy)),
                                       __fmul_rn(dz, dz));
            const bool in = valid && (d2 < R2);
            const unsigned long long mk = __ballot(in);
            const int pos = cnt + rank_before(mk);
            if (in && pos < CAP) cand[w][pos] = p;
            cnt += __popcll(mk);
        }
    }

    int eff;
    if (cnt == 0) {
        if (lane == 0) sel[w][0] = make_float4(nbb[0], nbb[1], nbb[2], 0.0f);
        eff = 1;
    } else if (cnt <= KSEL) {
        if (lane < cnt) sel[w][lane] = cand[w][lane];
        eff = cnt;
    } else if (cnt <= CAP) {
        float4 c0v = make_float4(0, 0, 0, 0), c1v = make_float4(0, 0, 0, 0);
        int i0 = 0x7fffffff, i1 = 0x7fffffff;
        if (lane < cnt)      { c0v = cand[w][lane];      i0 = __float_as_int(c0v.w); }
        if (lane + 64 < cnt) { c1v = cand[w][lane + 64]; i1 = __float_as_int(c1v.w); }
        int lo = 0, hi = MDIM - 1;   // smallest T with count(idx<=T) >= KSEL
        while (lo < hi) {
            const int mid = (lo + hi) >> 1;
            const int c = __popcll(__ballot(i0 <= mid)) + __popcll(__ballot(i1 <= mid));
            if (c >= KSEL) hi = mid; else lo = mid + 1;
        }
        const bool k0 = (i0 <= lo);
        const unsigned long long m0 = __ballot(k0);
        if (k0) sel[w][rank_before(m0)] = c0v;
        const int cc0 = __popcll(m0);
        const bool k1 = (i1 <= lo);
        const unsigned long long m1 = __ballot(k1);
        if (k1) sel[w][cc0 + rank_before(m1)] = c1v;
        eff = KSEL;
    } else {
        // overflow fallback (statistically never): ordered full scan, first K
        int c2 = 0;
        for (int base = 0; base < MDIM && c2 < KSEL; base += 64) {
            const int m = base + lane;
            const float* p = nbb + 3 * m;
            const float nx = p[0], ny = p[1], nz = p[2];
            const float dx = __fsub_rn(ax, nx);
            const float dy = __fsub_rn(ay, ny);
            const float dz = __fsub_rn(az, nz);
            const float d2 = __fadd_rn(__fadd_rn(__fmul_rn(dx, dx), __fmul_rn(dy, dy)),
                                       __fmul_rn(dz, dz));
            const bool in = d2 < R2;
            const unsigned long long mk = __ballot(in);
            const int pos = c2 + rank_before(mk);
            if (in && pos < KSEL) sel[w][pos] = make_float4(nx, ny, nz, 0.0f);
            c2 += __popcll(mk);
        }
        eff = KSEL;
    }

    const int eff4 = (eff + 3) & ~3;  // pad with a selected point: idempotent under max
    __builtin_amdgcn_wave_barrier();
    __builtin_amdgcn_s_waitcnt(0);
    if (lane >= eff && lane < eff4) {
        const float4 f = sel[w][0];
        sel[w][lane] = f;
    }
    __builtin_amdgcn_wave_barrier();

    float acc0 = -1e30f, acc1 = -1e30f;
    for (int j = 0; j < eff4; j += 4) {
        float p0[4], p1[4], sv[4];
        #pragma unroll
        for (int t = 0; t < 4; ++t) {
            const float4 v = sel[w][j + t];
            const float lx = fmaf(v.x, P.nka0.x, fmaf(v.y, P.nka1.x, fmaf(v.z, P.nka2.x, qax)));
            const float ly = fmaf(v.x, P.nka0.y, fmaf(v.y, P.nka1.y, fmaf(v.z, P.nka2.y, qay)));
            const float ex = exp2_hw(lx);
            const float ey = exp2_hw(ly);
            sv[t] = ex + ey;
            const float dx_ = fmaf(v.x, nwd0.x, fmaf(v.y, nwd1.x, fmaf(v.z, nwd2.x, adx)));
            const float dy_ = fmaf(v.x, nwd0.y, fmaf(v.y, nwd1.y, fmaf(v.z, nwd2.y, ady)));
            p0[t] = dx_ * ex;
            p1[t] = dy_ * ey;
        }
        #pragma unroll
        for (int t = 0; t < 4; ++t) sv[t] = dpp_add<DPP_QUAD_XOR1, 0xF>(sv[t]);
        #pragma unroll
        for (int t = 0; t < 4; ++t) sv[t] = dpp_add<DPP_QUAD_XOR2, 0xF>(sv[t]);
        #pragma unroll
        for (int t = 0; t < 4; ++t) sv[t] = dpp_add<DPP_ROW_HALF_MIRROR, 0xF>(sv[t]);
        #pragma unroll
        for (int t = 0; t < 4; ++t) sv[t] = dpp_add<DPP_ROW_MIRROR, 0xF>(sv[t]);
        #pragma unroll
        for (int t = 0; t < 4; ++t) sv[t] = dpp_add<DPP_ROW_BCAST15, 0xA>(sv[t]);
        #pragma unroll
        for (int t = 0; t < 4; ++t) sv[t] = dpp_add<DPP_ROW_BCAST31, 0xC>(sv[t]);
        #pragma unroll
        for (int t = 0; t < 4; ++t) {
            const float tot = __int_as_float(__builtin_amdgcn_readlane(__float_as_int(sv[t]), 63));
            const float inv = __builtin_amdgcn_rcpf(tot);
            acc0 = fmaxf(acc0, p0[t] * inv);
            acc1 = fmaxf(acc1, p1[t] * inv);
        }
    }
    float2 o; o.x = acc0; o.y = acc1;
    return o;
}

// ---------------------------------------------------------------------------
// fp64 folded-weight fold, work item i in [0, 7*128)
// ---------------------------------------------------------------------------
__device__ __forceinline__ void fold_one(int i, const float* Wq, const float* bq,
                                         const float* Wk, const float* bk,
                                         const float* Wa, const float* ba,
                                         float* pre) {
    const double LOG2E = 1.4426950408889634074;
    const int r = i >> 7, c = i & (CDIM - 1);
    if (r < 3) {
        double s0 = 0, s1 = 0, s2 = 0, s3 = 0;
        for (int k = 0; k < CDIM; k += 4) {
            s0 += (double)Wq[r * CDIM + k + 0] * (double)Wa[(k + 0) * CDIM + c];
            s1 += (double)Wq[r * CDIM + k + 1] * (double)Wa[(k + 1) * CDIM + c];
            s2 += (double)Wq[r * CDIM + k + 2] * (double)Wa[(k + 2) * CDIM + c];
            s3 += (double)Wq[r * CDIM + k + 3] * (double)Wa[(k + 3) * CDIM + c];
        }
        pre[r * CDIM + c] = (float)(((s0 + s1) + (s2 + s3)) * LOG2E);
    } else if (r < 6) {
        const int rr = r - 3;
        double s0 = 0, s1 = 0, s2 = 0, s3 = 0;
        for (int k = 0; k < CDIM; k += 4) {
            s0 += (double)Wk[rr * CDIM + k + 0] * (double)Wa[(k + 0) * CDIM + c];
            s1 += (double)Wk[rr * CDIM + k + 1] * (double)Wa[(k + 1) * CDIM + c];
            s2 += (double)Wk[rr * CDIM + k + 2] * (double)Wa[(k + 2) * CDIM + c];
            s3 += (double)Wk[rr * CDIM + k + 3] * (double)Wa[(k + 3) * CDIM + c];
        }
        pre[r * CDIM + c] = (float)(((s0 + s1) + (s2 + s3)) * (-LOG2E));  // negated
    } else {
        double s = (double)ba[c];
        for (int k = 0; k < CDIM; ++k)
            s += ((double)bq[k] - (double)bk[k]) * (double)Wa[k * CDIM + c];
        pre[6 * CDIM + c] = (float)(s * LOG2E);
    }
}

// ---------------------------------------------------------------------------
// COOPERATIVE fused kernel: blocks 0..3 bin batch b, block 4 folds weights,
// grid.sync(), then every block handles 8 anchors (2 per wave).
// ---------------------------------------------------------------------------
__launch_bounds__(256, 8)
__global__ void fused_kernel(const float* __restrict__ anchor,
                             const float* __restrict__ neighbor,
                             const float* __restrict__ Wq, const float* __restrict__ bq,
                             const float* __restrict__ Wk, const float* __restrict__ bk,
                             const float* __restrict__ Wa, const float* __restrict__ ba,
                             const float* __restrict__ Wd, const float* __restrict__ bd,
                             float* __restrict__ pre,
                             int* __restrict__ starts,
                             float4* __restrict__ pts4,
                             float* __restrict__ out) {
    __shared__ float4 cand[4][CAP];
    __shared__ float4 sel[4][KSEL];
    __shared__ int cnts[NCELL];
    __shared__ int curs[NCELL];

    const int blk = blockIdx.x;
    const int tid = threadIdx.x;
    const int w = tid >> 6, lane = tid & 63;

    // ---- setup phase (5 working blocks; rest wait at grid sync) ----
    if (blk < BDIM) {
        if (tid < NCELL) cnts[tid] = 0;
        __syncthreads();
        const float* nbb = neighbor + (size_t)blk * MDIM * 3;
        #pragma unroll 4
        for (int k = 0; k < 16; ++k) {
            const int i = tid + k * 256;
            const float z = nbb[3 * i + 2], y = nbb[3 * i + 1], x = nbb[3 * i];
            atomicAdd(&cnts[(cell_of(z) * 4 + cell_of(y)) * 4 + cell_of(x)], 1);
        }
        __syncthreads();
        if (tid < NCELL) {   // wave 0 exclusive scan over 64 cells
            const int v = cnts[tid];
            int inc = v;
            #pragma unroll
            for (int off = 1; off < 64; off <<= 1) {
                const int u = __shfl_up(inc, off);
                if (tid >= off) inc += u;
            }
            const int excl = inc - v;
            curs[tid] = excl;
            starts[blk * (NCELL + 1) + tid] = excl;
            if (tid == NCELL - 1) starts[blk * (NCELL + 1) + NCELL] = inc;
        }
        __syncthreads();
        #pragma unroll 4
        for (int k = 0; k < 16; ++k) {
            const int i = tid + k * 256;
            const float x = nbb[3 * i], y = nbb[3 * i + 1], z = nbb[3 * i + 2];
            const int cell = (cell_of(z) * 4 + cell_of(y)) * 4 + cell_of(x);
            const int slot = atomicAdd(&curs[cell], 1);
            pts4[(size_t)blk * MDIM + slot] = make_float4(x, y, z, __int_as_float(i));
        }
    } else if (blk == BDIM) {
        for (int i = tid; i < 7 * CDIM; i += 256)
            fold_one(i, Wq, bq, Wk, bk, Wa, ba, pre);
    }

    cg::this_grid().sync();   // device-scope barrier + memory ordering

    // ---- attn phase: 8 anchors per block, 2 sequential per wave ----
    const int b = blk >> 9;                 // 512 blocks per batch
    const int nbase = (blk & 511) << 3;
    const float* nbb = neighbor + (size_t)b * MDIM * 3;
    const float4* pb = pts4 + (size_t)b * MDIM;
    const int* st = starts + b * (NCELL + 1);

    LaneW P;
    load_lane_weights(P, pre, Wd, bd, lane);

    #pragma unroll
    for (int rep = 0; rep < 2; ++rep) {
        const int n = nbase + rep * 4 + w;
        const float* ap = anchor + ((size_t)b * NDIM + n) * 3;
        const float2 o = attn_core(w, lane, ap[0], ap[1], ap[2], P, nbb, pb, st, cand, sel);
        ((float2*)out)[((size_t)b * NDIM + n) * 64 + lane] = o;
    }
}

// ---------------------------------------------------------------------------
// Non-cooperative fallback path (proven R6 pipeline): setup + attn2.
// ---------------------------------------------------------------------------
__launch_bounds__(1024)
__global__ void setup_kernel(const float* __restrict__ neighbor,
                             const float* __restrict__ Wq, const float* __restrict__ bq,
                             const float* __restrict__ Wk, const float* __restrict__ bk,
                             const float* __restrict__ Wa, const float* __restrict__ ba,
                             float* __restrict__ pre,
                             int* __restrict__ starts,
                             float4* __restrict__ pts4,
                             const int do_bins) {
    const int blk = blockIdx.x;
    const int t = threadIdx.x;
    if (do_bins && blk < BDIM) {
        __shared__ int cnts[NCELL];
        __shared__ int curs[NCELL];
        if (t < NCELL) cnts[t] = 0;
        __syncthreads();
        const float* nbb = neighbor + (size_t)blk * MDIM * 3;
        float px[4], py[4], pz[4];
        int cell[4];
        #pragma unroll
        for (int k = 0; k < 4; ++k) {
            const int i = t + k * 1024;
            const float x = nbb[3 * i], y = nbb[3 * i + 1], z = nbb[3 * i + 2];
            px[k] = x; py[k] = y; pz[k] = z;
            cell[k] = (cell_of(z) * 4 + cell_of(y)) * 4 + cell_of(x);
            atomicAdd(&cnts[cell[k]], 1);
        }
        __syncthreads();
        if (t < NCELL) {
            const int v = cnts[t];
            int inc = v;
            #pragma unroll
            for (int off = 1; off < 64; off <<= 1) {
                const int u = __shfl_up(inc, off);
                if (t >= off) inc += u;
            }
            const int excl = inc - v;
            curs[t] = excl;
            starts[blk * (NCELL + 1) + t] = excl;
            if (t == NCELL - 1) starts[blk * (NCELL + 1) + NCELL] = inc;
        }
        __syncthreads();
        #pragma unroll
        for (int k = 0; k < 4; ++k) {
            const int i = t + k * 1024;
            const int slot = atomicAdd(&curs[cell[k]], 1);
            pts4[(size_t)blk * MDIM + slot] = make_float4(px[k], py[k], pz[k], __int_as_float(i));
        }
    } else if (!do_bins || blk == BDIM) {
        if (t < 7 * CDIM) fold_one(t, Wq, bq, Wk, bk, Wa, ba, pre);
    }
}

__launch_bounds__(256)
__global__ void attn2_kernel(const float* __restrict__ anchor,
                             const float* __restrict__ neighbor,
                             const float* __restrict__ Wd,
                             const float* __restrict__ bd,
                             const float* __restrict__ pre,
                             const float4* __restrict__ pts4,
                             const int* __restrict__ starts,
                             float* __restrict__ out) {
    __shared__ float4 cand[4][CAP];
    __shared__ float4 sel[4][KSEL];

    const int b    = blockIdx.x >> 10;
    const int n0   = (blockIdx.x & 1023) << 2;
    const int tid  = threadIdx.x;
    const int w    = tid >> 6;
    const int lane = tid & 63;

    const int n = n0 + w;
    const float* ap = anchor + ((size_t)b * NDIM + n) * 3;
    const float* nbb = neighbor + (size_t)b * MDIM * 3;
    const float4* pb = pts4 + (size_t)b * MDIM;
    const int* st = starts + b * (NCELL + 1);

    LaneW P;
    load_lane_weights(P, pre, Wd, bd, lane);
    const float2 o = attn_core(w, lane, ap[0], ap[1], ap[2], P, nbb, pb, st, cand, sel);
    ((float2*)out)[((size_t)b * NDIM + n) * 64 + lane] = o;
}

// full-scan fallback for tiny ws (no bins): scan all M, ordered early-exit
__launch_bounds__(256)
__global__ void attn_fallback(const float* __restrict__ anchor,
                              const float* __restrict__ neighbor,
                              const float* __restrict__ Wd,
                              const float* __restrict__ bd,
                              const float* __restrict__ pre,
                              float* __restrict__ out) {
    __shared__ float4 sel[4][KSEL];
    __shared__ int lists[4][KSEL];

    const int b = blockIdx.x >> 10, n0 = (blockIdx.x & 1023) << 2;
    const int tid = threadIdx.x, w = tid >> 6, lane = tid & 63;
    const int n = n0 + w;
    const float* ap = anchor + ((size_t)b * NDIM + n) * 3;
    const float ax = ap[0], ay = ap[1], az = ap[2];
    const float* nbb = neighbor + (size_t)b * MDIM * 3;

    LaneW P;
    load_lane_weights(P, pre, Wd, bd, lane);
    const float qax = fmaf(ax, P.wqa0.x, fmaf(ay, P.wqa1.x, fmaf(az, P.wqa2.x, P.cav.x)));
    const float qay = fmaf(ax, P.wqa0.y, fmaf(ay, P.wqa1.y, fmaf(az, P.wqa2.y, P.cav.y)));
    const float adx = fmaf(ax, P.wd0.x, fmaf(ay, P.wd1.x, fmaf(az, P.wd2.x, P.bdv.x)));
    const float ady = fmaf(ax, P.wd0.y, fmaf(ay, P.wd1.y, fmaf(az, P.wd2.y, P.bdv.y)));
    const v2f nwd0 = -P.wd0, nwd1 = -P.wd1, nwd2 = -P.wd2;

    constexpr float R2 = (float)(0.12 * 0.12);
    int cnt = 0;
    for (int base = 0; base < MDIM && cnt < KSEL; base += 64) {
        const int m = base + lane;
        const float* p = nbb + 3 * m;
        const float dx = __fsub_rn(ax, p[0]);
        const float dy = __fsub_rn(ay, p[1]);
        const float dz = __fsub_rn(az, p[2]);
        const float d2 = __fadd_rn(__fadd_rn(__fmul_rn(dx, dx), __fmul_rn(dy, dy)),
                                   __fmul_rn(dz, dz));
        const bool in = d2 < R2;
        const unsigned long long mk = __ballot(in);
        const int pos = cnt + rank_before(mk);
        if (in && pos < KSEL) lists[w][pos] = m;
        cnt += __popcll(mk);
    }
    int eff = cnt < KSEL ? cnt : KSEL;
    if (cnt == 0) { if (lane == 0) lists[w][0] = 0; eff = 1; }
    const int eff4 = (eff + 3) & ~3;
    if (lane == 0) for (int j = eff; j < eff4; ++j) lists[w][j] = lists[w][0];
    __builtin_amdgcn_wave_barrier();
    if (lane < eff4) {
        const float* p = nbb + 3 * lists[w][lane];
        sel[w][lane] = make_float4(p[0], p[1], p[2], 0.f);
    }
    __builtin_amdgcn_wave_barrier();

    float acc0 = -1e30f, acc1 = -1e30f;
    for (int j = 0; j < eff4; j += 4) {
        float p0[4], p1[4], sv[4];
        #pragma unroll
        for (int t = 0; t < 4; ++t) {
            const float4 v = sel[w][j + t];
            const float lx = fmaf(v.x, P.nka0.x, fmaf(v.y, P.nka1.x, fmaf(v.z, P.nka2.x, qax)));
            const float ly = fmaf(v.x, P.nka0.y, fmaf(v.y, P.nka1.y, fmaf(v.z, P.nka2.y, qay)));
            const float ex = exp2_hw(lx);
            const float ey = exp2_hw(ly);
            sv[t] = ex + ey;
            const float dx_ = fmaf(v.x, nwd0.x, fmaf(v.y, nwd1.x, fmaf(v.z, nwd2.x, adx)));
            const float dy_ = fmaf(v.x, nwd0.y, fmaf(v.y, nwd1.y, fmaf(v.z, nwd2.y, ady)));
            p0[t] = dx_ * ex;
            p1[t] = dy_ * ey;
        }
        #pragma unroll
        for (int t = 0; t < 4; ++t) sv[t] = dpp_add<DPP_QUAD_XOR1, 0xF>(sv[t]);
        #pragma unroll
        for (int t = 0; t < 4; ++t) sv[t] = dpp_add<DPP_QUAD_XOR2, 0xF>(sv[t]);
        #pragma unroll
        for (int t = 0; t < 4; ++t) sv[t] = dpp_add<DPP_ROW_HALF_MIRROR, 0xF>(sv[t]);
        #pragma unroll
        for (int t = 0; t < 4; ++t) sv[t] = dpp_add<DPP_ROW_MIRROR, 0xF>(sv[t]);
        #pragma unroll
        for (int t = 0; t < 4; ++t) sv[t] = dpp_add<DPP_ROW_BCAST15, 0xA>(sv[t]);
        #pragma unroll
        for (int t = 0; t < 4; ++t) sv[t] = dpp_add<DPP_ROW_BCAST31, 0xC>(sv[t]);
        #pragma unroll
        for (int t = 0; t < 4; ++t) {
            const float tot = __int_as_float(__builtin_amdgcn_readlane(__float_as_int(sv[t]), 63));
            const float inv = __builtin_amdgcn_rcpf(tot);
            acc0 = fmaxf(acc0, p0[t] * inv);
            acc1 = fmaxf(acc1, p1[t] * inv);
        }
    }
    float2 o; o.x = acc0; o.y = acc1;
    ((float2*)out)[((size_t)b * NDIM + n) * 64 + lane] = o;
}

extern "C" void kernel_launch(void* const* d_in, const int* in_sizes, int n_in,
                              void* d_out, int out_size, void* d_ws, size_t ws_size,
                              hipStream_t stream) {
    const float* anchor   = (const float*)d_in[0];
    const float* neighbor = (const float*)d_in[1];
    const float* Wq = (const float*)d_in[2];
    const float* bq = (const float*)d_in[3];
    const float* Wk = (const float*)d_in[4];
    const float* bk = (const float*)d_in[5];
    const float* Wd = (const float*)d_in[6];
    const float* bd = (const float*)d_in[7];
    const float* Wa = (const float*)d_in[8];
    const float* ba = (const float*)d_in[9];
    float* out = (float*)d_out;

    float* pre   = (float*)d_ws;
    int* starts  = (int*)((char*)d_ws + PRE_BYTES);
    float4* pts4 = (float4*)((char*)d_ws + PTS4_OFF);

    if (ws_size >= WS_NEEDED) {
        // try cooperative single-dispatch; requires full grid co-residency
        int dev = 0;
        int coop_ok = 0;
        if (hipGetDevice(&dev) == hipSuccess) {
            hipDeviceProp_t prop;
            int maxBlk = 0;
            if (hipGetDeviceProperties(&prop, dev) == hipSuccess &&
                prop.cooperativeLaunch &&
                hipOccupancyMaxActiveBlocksPerMultiprocessor(
                    &maxBlk, (const void*)fused_kernel, 256, 0) == hipSuccess &&
                (long long)maxBlk * prop.multiProcessorCount >= GRID_COOP) {
                coop_ok = 1;
            }
        }
        if (coop_ok) {
            void* args[] = { (void*)&anchor, (void*)&neighbor,
                             (void*)&Wq, (void*)&bq, (void*)&Wk, (void*)&bk,
                             (void*)&Wa, (void*)&ba, (void*)&Wd, (void*)&bd,
                             (void*)&pre, (void*)&starts, (void*)&pts4, (void*)&out };
            if (hipLaunchCooperativeKernel((const void*)fused_kernel,
                                           dim3(GRID_COOP), dim3(256),
                                           args, 0, stream) == hipSuccess) {
                return;
            }
        }
        // fallback: proven two-dispatch pipeline
        setup_kernel<<<dim3(BDIM + 1), dim3(1024), 0, stream>>>(
            neighbor, Wq, bq, Wk, bk, Wa, ba, pre, starts, pts4, 1);
        attn2_kernel<<<dim3(BDIM * NDIM / 4), dim3(256), 0, stream>>>(
            anchor, neighbor, Wd, bd, pre, pts4, starts, out);
    } else {
        setup_kernel<<<dim3(1), dim3(1024), 0, stream>>>(
            neighbor, Wq, bq, Wk, bk, Wa, ba, pre, starts, pts4, 0);
        attn_fallback<<<dim3(BDIM * NDIM / 4), dim3(256), 0, stream>>>(
            anchor, neighbor, Wd, bd, pre, out);
    }
}

// Round 8
// 115.008 us; speedup vs baseline: 1.2445x; 1.0226x over previous
//
#include <hip/hip_runtime.h>
#include <math.h>

#define BDIM 4
#define NDIM 4096
#define MDIM 4096
#define CDIM 128
#define KSEL 32
#define NCELL 64     // 4x4x4 grid, cell 0.25 >= 2*r widened => ball spans <=2 cells/dim
#define CAP 128      // per-wave candidate cap (expected ~30 hits; P(>128) ~ 0)

typedef float v2f __attribute__((ext_vector_type(2)));

// ws layout: pre[7*C] floats | starts[(NCELL+1)*BDIM] ints | pts4[B*M] float4
#define PRE_BYTES (7 * CDIM * 4)                       // 3584
#define STARTS_BYTES ((NCELL + 1) * BDIM * 4)          // 1040
#define PTS4_OFF (PRE_BYTES + STARTS_BYTES)            // 4624 (16B aligned)
#define WS_NEEDED (PTS4_OFF + (size_t)BDIM * MDIM * 16)

// ---------------------------------------------------------------------------
// helpers
// ---------------------------------------------------------------------------
__device__ __forceinline__ float exp2_hw(float x) {   // bare v_exp_f32 (~1 ulp)
    float r;
    asm("v_exp_f32 %0, %1" : "=v"(r) : "v"(x));
    return r;
}

template <int CTRL, int MASK>
__device__ __forceinline__ float dpp_add(float x) {   // VALU-pipe reduction step
    const int r = __builtin_amdgcn_update_dpp(0, __float_as_int(x), CTRL, MASK, 0xF, true);
    return x + __int_as_float(r);
}
#define DPP_QUAD_XOR1 0xB1
#define DPP_QUAD_XOR2 0x4E
#define DPP_ROW_HALF_MIRROR 0x141
#define DPP_ROW_MIRROR      0x140
#define DPP_ROW_BCAST15     0x142
#define DPP_ROW_BCAST31     0x143

// # set bits of mk in lanes strictly below this lane (v_mbcnt_lo+hi)
__device__ __forceinline__ int rank_before(unsigned long long mk) {
    return __builtin_amdgcn_mbcnt_hi((unsigned)(mk >> 32),
                                     __builtin_amdgcn_mbcnt_lo((unsigned)mk, 0));
}

__device__ __forceinline__ int cell_of(float v) {
    int c = (int)(v * 4.0f);
    return c < 0 ? 0 : (c > 3 ? 3 : c);
}

__device__ __forceinline__ v2f splat(float x) { v2f r; r.x = x; r.y = x; return r; }

// packed fma: lowers to v_pk_fma_f32 (full-rate, 2 fp32 FMA / inst)
__device__ __forceinline__ v2f pk_fma(v2f a, v2f b, v2f c) {
    return __builtin_elementwise_fma(a, b, c);
}

// per-lane channel-pair weights (2 channels per lane)
struct LaneW {
    v2f wqa0, wqa1, wqa2;   // (Wq@Wa)*log2e
    v2f nka0, nka1, nka2;   // -(Wk@Wa)*log2e  (pre-negated)
    v2f cav;                // ((bq-bk)@Wa+ba)*log2e
    v2f wd0, wd1, wd2, bdv; // raw Wd rows + bd
};

__device__ __forceinline__ void load_lane_weights(LaneW& P, const float* pre,
                                                  const float* Wd, const float* bd, int lane) {
    const v2f* pre2 = (const v2f*)pre;
    const v2f* wdp  = (const v2f*)Wd;
    const v2f* bdp  = (const v2f*)bd;
    P.wqa0 = pre2[0 * 64 + lane]; P.wqa1 = pre2[1 * 64 + lane]; P.wqa2 = pre2[2 * 64 + lane];
    P.nka0 = pre2[3 * 64 + lane]; P.nka1 = pre2[4 * 64 + lane]; P.nka2 = pre2[5 * 64 + lane];
    P.cav  = pre2[6 * 64 + lane];
    P.wd0 = wdp[0 * 64 + lane]; P.wd1 = wdp[1 * 64 + lane]; P.wd2 = wdp[2 * 64 + lane];
    P.bdv = bdp[lane];
}

// ---------------------------------------------------------------------------
// fp64 folded-weight fold, work item i in [0, 7*128)
// ---------------------------------------------------------------------------
__device__ __forceinline__ void fold_one(int i, const float* Wq, const float* bq,
                                         const float* Wk, const float* bk,
                                         const float* Wa, const float* ba,
                                         float* pre) {
    const double LOG2E = 1.4426950408889634074;
    const int r = i >> 7, c = i & (CDIM - 1);
    if (r < 3) {
        double s0 = 0, s1 = 0, s2 = 0, s3 = 0;
        for (int k = 0; k < CDIM; k += 4) {
            s0 += (double)Wq[r * CDIM + k + 0] * (double)Wa[(k + 0) * CDIM + c];
            s1 += (double)Wq[r * CDIM + k + 1] * (double)Wa[(k + 1) * CDIM + c];
            s2 += (double)Wq[r * CDIM + k + 2] * (double)Wa[(k + 2) * CDIM + c];
            s3 += (double)Wq[r * CDIM + k + 3] * (double)Wa[(k + 3) * CDIM + c];
        }
        pre[r * CDIM + c] = (float)(((s0 + s1) + (s2 + s3)) * LOG2E);
    } else if (r < 6) {
        const int rr = r - 3;
        double s0 = 0, s1 = 0, s2 = 0, s3 = 0;
        for (int k = 0; k < CDIM; k += 4) {
            s0 += (double)Wk[rr * CDIM + k + 0] * (double)Wa[(k + 0) * CDIM + c];
            s1 += (double)Wk[rr * CDIM + k + 1] * (double)Wa[(k + 1) * CDIM + c];
            s2 += (double)Wk[rr * CDIM + k + 2] * (double)Wa[(k + 2) * CDIM + c];
            s3 += (double)Wk[rr * CDIM + k + 3] * (double)Wa[(k + 3) * CDIM + c];
        }
        pre[r * CDIM + c] = (float)(((s0 + s1) + (s2 + s3)) * (-LOG2E));  // negated
    } else {
        double s = (double)ba[c];
        for (int k = 0; k < CDIM; ++k)
            s += ((double)bq[k] - (double)bk[k]) * (double)Wa[k * CDIM + c];
        pre[6 * CDIM + c] = (float)(s * LOG2E);
    }
}

// ---------------------------------------------------------------------------
// Fused setup (R6-proven): blocks 0..3 bin batch b, block 4 folds weights.
// ---------------------------------------------------------------------------
__launch_bounds__(1024)
__global__ void setup_kernel(const float* __restrict__ neighbor,
                             const float* __restrict__ Wq, const float* __restrict__ bq,
                             const float* __restrict__ Wk, const float* __restrict__ bk,
                             const float* __restrict__ Wa, const float* __restrict__ ba,
                             float* __restrict__ pre,
                             int* __restrict__ starts,
                             float4* __restrict__ pts4,
                             const int do_bins) {
    const int blk = blockIdx.x;
    const int t = threadIdx.x;
    if (do_bins && blk < BDIM) {
        __shared__ int cnts[NCELL];
        __shared__ int curs[NCELL];
        if (t < NCELL) cnts[t] = 0;
        __syncthreads();
        const float* nbb = neighbor + (size_t)blk * MDIM * 3;
        float px[4], py[4], pz[4];
        int cell[4];
        #pragma unroll
        for (int k = 0; k < 4; ++k) {
            const int i = t + k * 1024;
            const float x = nbb[3 * i], y = nbb[3 * i + 1], z = nbb[3 * i + 2];
            px[k] = x; py[k] = y; pz[k] = z;
            cell[k] = (cell_of(z) * 4 + cell_of(y)) * 4 + cell_of(x);
            atomicAdd(&cnts[cell[k]], 1);
        }
        __syncthreads();
        if (t < NCELL) {   // wave 0 exclusive scan over 64 cells
            const int v = cnts[t];
            int inc = v;
            #pragma unroll
            for (int off = 1; off < 64; off <<= 1) {
                const int u = __shfl_up(inc, off);
                if (t >= off) inc += u;
            }
            const int excl = inc - v;
            curs[t] = excl;
            starts[blk * (NCELL + 1) + t] = excl;
            if (t == NCELL - 1) starts[blk * (NCELL + 1) + NCELL] = inc;
        }
        __syncthreads();
        #pragma unroll
        for (int k = 0; k < 4; ++k) {
            const int i = t + k * 1024;
            const int slot = atomicAdd(&curs[cell[k]], 1);
            pts4[(size_t)blk * MDIM + slot] = make_float4(px[k], py[k], pz[k], __int_as_float(i));
        }
    } else if (!do_bins || blk == BDIM) {
        if (t < 7 * CDIM) fold_one(t, Wq, bq, Wk, bk, Wa, ba, pre);
    }
}

// ---------------------------------------------------------------------------
// Main kernel: 1 wave per anchor, 4 independent waves / 256-thread block.
// Phase 1: binned candidate scan; hits pos<KSEL written DIRECTLY to sel,
//          overflow to cand (so cnt<=K needs no copy). Exact no-fma d2 test.
// Selection (cnt>K): 12-iter ballot binary-search on index threshold over the
//          split sel/cand layout; winners compacted into sel.
// Phase 2: packed fp32 (v_pk_fma/mul/max) logits+dis, bare v_exp_f32,
//          DPP wave64 softmax denominator.
// ---------------------------------------------------------------------------
__launch_bounds__(256)
__global__ void attn2_kernel(const float* __restrict__ anchor,
                             const float* __restrict__ neighbor,
                             const float* __restrict__ Wd,
                             const float* __restrict__ bd,
                             const float* __restrict__ pre,
                             const float4* __restrict__ pts4,
                             const int* __restrict__ starts,
                             float* __restrict__ out) {
    __shared__ float4 cand[4][CAP - KSEL];
    __shared__ float4 sel[4][KSEL];

    const int b    = blockIdx.x >> 10;
    const int n0   = (blockIdx.x & 1023) << 2;
    const int tid  = threadIdx.x;
    const int w    = tid >> 6;
    const int lane = tid & 63;

    const int n = n0 + w;
    const float* ap = anchor + ((size_t)b * NDIM + n) * 3;
    const float ax = ap[0], ay = ap[1], az = ap[2];
    const float* nbb = neighbor + (size_t)b * MDIM * 3;

    LaneW P;
    load_lane_weights(P, pre, Wd, bd, lane);

    const v2f axv = splat(ax), ayv = splat(ay), azv = splat(az);
    const v2f qa = pk_fma(axv, P.wqa0, pk_fma(ayv, P.wqa1, pk_fma(azv, P.wqa2, P.cav)));
    const v2f ad = pk_fma(axv, P.wd0, pk_fma(ayv, P.wd1, pk_fma(azv, P.wd2, P.bdv)));
    const v2f nwd0 = -P.wd0, nwd1 = -P.wd1, nwd2 = -P.wd2;

    // --- phase 1: binned candidate collection ---
    constexpr float R2 = (float)(0.12 * 0.12);
    const float RP = 0.1201f;   // widened; 2*RP < 0.25 => <=2 cells/dim always

    const int cx0 = max(0, (int)((ax - RP) * 4.0f)), cx1 = min(3, (int)((ax + RP) * 4.0f));
    const int cy0 = max(0, (int)((ay - RP) * 4.0f)), cy1 = min(3, (int)((ay + RP) * 4.0f));
    const int cz0 = max(0, (int)((az - RP) * 4.0f)), cz1 = min(3, (int)((az + RP) * 4.0f));

    const float4* pb = pts4 + (size_t)b * MDIM;
    const int* st = starts + b * (NCELL + 1);

    int rs[4], re[4];
    int nr = 0;
    for (int cz = cz0; cz <= cz1; ++cz)
        for (int cy = cy0; cy <= cy1; ++cy) {
            const int crow = (cz * 4 + cy) * 4;
            rs[nr] = st[crow + cx0];
            re[nr] = st[crow + cx1 + 1];
            ++nr;
        }

    int cnt = 0;
    for (int r = 0; r < nr; ++r) {
        const int rend = re[r];
        for (int base = rs[r]; base < rend; base += 64) {
            const int i = base + lane;
            const float4 p = pb[min(i, rend - 1)];   // clamped load; validity via flag
            const float dx = __fsub_rn(ax, p.x);
            const float dy = __fsub_rn(ay, p.y);
            const float dz = __fsub_rn(az, p.z);
            const float d2 = __fadd_rn(__fadd_rn(__fmul_rn(dx, dx), __fmul_rn(dy, dy)),
                                       __fmul_rn(dz, dz));
            const bool in = (i < rend) && (d2 < R2);
            const unsigned long long mk = __ballot(in);
            const int pos = cnt + rank_before(mk);
            if (in && pos < CAP) {
                if (pos < KSEL) sel[w][pos] = p;
                else            cand[w][pos - KSEL] = p;
            }
            cnt += __popcll(mk);
        }
    }

    // --- selection: the K smallest original indices among hits ---
    int eff;
    if (cnt == 0) {
        if (lane == 0) sel[w][0] = make_float4(nbb[0], nbb[1], nbb[2], 0.0f);
        eff = 1;
    } else if (cnt <= KSEL) {
        eff = cnt;                       // sel already holds them, in hit order
    } else if (cnt <= CAP) {
        // gather hit h for this lane: h<KSEL -> sel[h], else cand[h-KSEL]
        float4 c0v = make_float4(0, 0, 0, 0), c1v = make_float4(0, 0, 0, 0);
        int i0 = 0x7fffffff, i1 = 0x7fffffff;
        if (lane < cnt) {
            c0v = (lane < KSEL) ? sel[w][lane] : cand[w][lane - KSEL];
            i0 = __float_as_int(c0v.w);
        }
        if (lane + 64 < cnt) {
            c1v = cand[w][lane + 64 - KSEL];
            i1 = __float_as_int(c1v.w);
        }
        int lo = 0, hi = MDIM - 1;   // smallest T with count(idx<=T) >= KSEL
        while (lo < hi) {
            const int mid = (lo + hi) >> 1;
            const int c = __popcll(__ballot(i0 <= mid)) + __popcll(__ballot(i1 <= mid));
            if (c >= KSEL) hi = mid; else lo = mid + 1;
        }
        __builtin_amdgcn_wave_barrier();   // reads above complete before sel rewrite
        const bool k0 = (i0 <= lo);
        const unsigned long long m0 = __ballot(k0);
        if (k0) sel[w][rank_before(m0)] = c0v;
        const int cc0 = __popcll(m0);
        const bool k1 = (i1 <= lo);
        const unsigned long long m1 = __ballot(k1);
        if (k1) sel[w][cc0 + rank_before(m1)] = c1v;
        eff = KSEL;
    } else {
        // overflow fallback (statistically never): ordered full scan, first K
        int c2 = 0;
        for (int base = 0; base < MDIM && c2 < KSEL; base += 64) {
            const int m = base + lane;
            const float* p = nbb + 3 * m;
            const float nx = p[0], ny = p[1], nz = p[2];
            const float dx = __fsub_rn(ax, nx);
            const float dy = __fsub_rn(ay, ny);
            const float dz = __fsub_rn(az, nz);
            const float d2 = __fadd_rn(__fadd_rn(__fmul_rn(dx, dx), __fmul_rn(dy, dy)),
                                       __fmul_rn(dz, dz));
            const bool in = d2 < R2;
            const unsigned long long mk = __ballot(in);
            const int pos = c2 + rank_before(mk);
            if (in && pos < KSEL) sel[w][pos] = make_float4(nx, ny, nz, 0.0f);
            c2 += __popcll(mk);
        }
        eff = KSEL;
    }

    const int eff4 = (eff + 3) & ~3;  // pad with a selected point: idempotent under max
    __builtin_amdgcn_wave_barrier();
    __builtin_amdgcn_s_waitcnt(0);
    if (lane >= eff && lane < eff4) {
        const float4 f = sel[w][0];
        sel[w][lane] = f;
    }
    __builtin_amdgcn_wave_barrier();

    // --- phase 2: packed channel softmax (exp2 domain) + max-accumulate ---
    v2f acc = splat(-1e30f);
    for (int j = 0; j < eff4; j += 4) {
        v2f pr[4];
        float sv[4];
        #pragma unroll
        for (int t = 0; t < 4; ++t) {
            const float4 v = sel[w][j + t];
            const v2f vx = splat(v.x), vy = splat(v.y), vz = splat(v.z);
            const v2f l = pk_fma(vx, P.nka0, pk_fma(vy, P.nka1, pk_fma(vz, P.nka2, qa)));
            v2f e; e.x = exp2_hw(l.x); e.y = exp2_hw(l.y);
            sv[t] = e.x + e.y;
            const v2f d = pk_fma(vx, nwd0, pk_fma(vy, nwd1, pk_fma(vz, nwd2, ad)));
            pr[t] = d * e;   // v_pk_mul_f32
        }
        #pragma unroll
        for (int t = 0; t < 4; ++t) sv[t] = dpp_add<DPP_QUAD_XOR1, 0xF>(sv[t]);
        #pragma unroll
        for (int t = 0; t < 4; ++t) sv[t] = dpp_add<DPP_QUAD_XOR2, 0xF>(sv[t]);
        #pragma unroll
        for (int t = 0; t < 4; ++t) sv[t] = dpp_add<DPP_ROW_HALF_MIRROR, 0xF>(sv[t]);
        #pragma unroll
        for (int t = 0; t < 4; ++t) sv[t] = dpp_add<DPP_ROW_MIRROR, 0xF>(sv[t]);
        #pragma unroll
        for (int t = 0; t < 4; ++t) sv[t] = dpp_add<DPP_ROW_BCAST15, 0xA>(sv[t]);
        #pragma unroll
        for (int t = 0; t < 4; ++t) sv[t] = dpp_add<DPP_ROW_BCAST31, 0xC>(sv[t]);
        #pragma unroll
        for (int t = 0; t < 4; ++t) {
            const float tot = __int_as_float(__builtin_amdgcn_readlane(__float_as_int(sv[t]), 63));
            const v2f iv = splat(__builtin_amdgcn_rcpf(tot));
            acc = __builtin_elementwise_max(acc, pr[t] * iv);   // pk_mul + pk_max
        }
    }

    float2 o; o.x = acc.x; o.y = acc.y;
    ((float2*)out)[((size_t)b * NDIM + n) * 64 + lane] = o;
}

// ---------------------------------------------------------------------------
// Fallback (ws too small for bins): full-scan kernel (ordered early-exit).
// ---------------------------------------------------------------------------
__launch_bounds__(256)
__global__ void attn_fallback(const float* __restrict__ anchor,
                              const float* __restrict__ neighbor,
                              const float* __restrict__ Wd,
                              const float* __restrict__ bd,
                              const float* __restrict__ pre,
                              float* __restrict__ out) {
    __shared__ float4 sel[4][KSEL];
    __shared__ int lists[4][KSEL];

    const int b = blockIdx.x >> 10, n0 = (blockIdx.x & 1023) << 2;
    const int tid = threadIdx.x, w = tid >> 6, lane = tid & 63;
    const int n = n0 + w;
    const float* ap = anchor + ((size_t)b * NDIM + n) * 3;
    const float ax = ap[0], ay = ap[1], az = ap[2];
    const float* nbb = neighbor + (size_t)b * MDIM * 3;

    LaneW P;
    load_lane_weights(P, pre, Wd, bd, lane);
    const v2f axv = splat(ax), ayv = splat(ay), azv = splat(az);
    const v2f qa = pk_fma(axv, P.wqa0, pk_fma(ayv, P.wqa1, pk_fma(azv, P.wqa2, P.cav)));
    const v2f ad = pk_fma(axv, P.wd0, pk_fma(ayv, P.wd1, pk_fma(azv, P.wd2, P.bdv)));
    const v2f nwd0 = -P.wd0, nwd1 = -P.wd1, nwd2 = -P.wd2;

    constexpr float R2 = (float)(0.12 * 0.12);
    int cnt = 0;
    for (int base = 0; base < MDIM && cnt < KSEL; base += 64) {
        const int m = base + lane;
        const float* p = nbb + 3 * m;
        const float dx = __fsub_rn(ax, p[0]);
        const float dy = __fsub_rn(ay, p[1]);
        const float dz = __fsub_rn(az, p[2]);
        const float d2 = __fadd_rn(__fadd_rn(__fmul_rn(dx, dx), __fmul_rn(dy, dy)),
                                   __fmul_rn(dz, dz));
        const bool in = d2 < R2;
        const unsigned long long mk = __ballot(in);
        const int pos = cnt + rank_before(mk);
        if (in && pos < KSEL) lists[w][pos] = m;
        cnt += __popcll(mk);
    }
    int eff = cnt < KSEL ? cnt : KSEL;
    if (cnt == 0) { if (lane == 0) lists[w][0] = 0; eff = 1; }
    const int eff4 = (eff + 3) & ~3;
    if (lane == 0) for (int j = eff; j < eff4; ++j) lists[w][j] = lists[w][0];
    __builtin_amdgcn_wave_barrier();
    if (lane < eff4) {
        const float* p = nbb + 3 * lists[w][lane];
        sel[w][lane] = make_float4(p[0], p[1], p[2], 0.f);
    }
    __builtin_amdgcn_wave_barrier();

    v2f acc = splat(-1e30f);
    for (int j = 0; j < eff4; j += 4) {
        v2f pr[4]; float sv[4];
        #pragma unroll
        for (int t = 0; t < 4; ++t) {
            const float4 v = sel[w][j + t];
            const v2f vx = splat(v.x), vy = splat(v.y), vz = splat(v.z);
            const v2f l = pk_fma(vx, P.nka0, pk_fma(vy, P.nka1, pk_fma(vz, P.nka2, qa)));
            v2f e; e.x = exp2_hw(l.x); e.y = exp2_hw(l.y);
            sv[t] = e.x + e.y;
            const v2f d = pk_fma(vx, nwd0, pk_fma(vy, nwd1, pk_fma(vz, nwd2, ad)));
            pr[t] = d * e;
        }
        #pragma unroll
        for (int t = 0; t < 4; ++t) sv[t] = dpp_add<DPP_QUAD_XOR1, 0xF>(sv[t]);
        #pragma unroll
        for (int t = 0; t < 4; ++t) sv[t] = dpp_add<DPP_QUAD_XOR2, 0xF>(sv[t]);
        #pragma unroll
        for (int t = 0; t < 4; ++t) sv[t] = dpp_add<DPP_ROW_HALF_MIRROR, 0xF>(sv[t]);
        #pragma unroll
        for (int t = 0; t < 4; ++t) sv[t] = dpp_add<DPP_ROW_MIRROR, 0xF>(sv[t]);
        #pragma unroll
        for (int t = 0; t < 4; ++t) sv[t] = dpp_add<DPP_ROW_BCAST15, 0xA>(sv[t]);
        #pragma unroll
        for (int t = 0; t < 4; ++t) sv[t] = dpp_add<DPP_ROW_BCAST31, 0xC>(sv[t]);
        #pragma unroll
        for (int t = 0; t < 4; ++t) {
            const float tot = __int_as_float(__builtin_amdgcn_readlane(__float_as_int(sv[t]), 63));
            const v2f iv = splat(__builtin_amdgcn_rcpf(tot));
            acc = __builtin_elementwise_max(acc, pr[t] * iv);
        }
    }
    float2 o; o.x = acc.x; o.y = acc.y;
    ((float2*)out)[((size_t)b * NDIM + n) * 64 + lane] = o;
}

extern "C" void kernel_launch(void* const* d_in, const int* in_sizes, int n_in,
                              void* d_out, int out_size, void* d_ws, size_t ws_size,
                              hipStream_t stream) {
    const float* anchor   = (const float*)d_in[0];
    const float* neighbor = (const float*)d_in[1];
    const float* Wq = (const float*)d_in[2];
    const float* bq = (const float*)d_in[3];
    const float* Wk = (const float*)d_in[4];
    const float* bk = (const float*)d_in[5];
    const float* Wd = (const float*)d_in[6];
    const float* bd = (const float*)d_in[7];
    const float* Wa = (const float*)d_in[8];
    const float* ba = (const float*)d_in[9];
    float* out = (float*)d_out;

    float* pre   = (float*)d_ws;
    int* starts  = (int*)((char*)d_ws + PRE_BYTES);
    float4* pts4 = (float4*)((char*)d_ws + PTS4_OFF);

    if (ws_size >= WS_NEEDED) {
        setup_kernel<<<dim3(BDIM + 1), dim3(1024), 0, stream>>>(
            neighbor, Wq, bq, Wk, bk, Wa, ba, pre, starts, pts4, 1);
        attn2_kernel<<<dim3(BDIM * NDIM / 4), dim3(256), 0, stream>>>(
            anchor, neighbor, Wd, bd, pre, pts4, starts, out);
    } else {
        setup_kernel<<<dim3(1), dim3(1024), 0, stream>>>(
            neighbor, Wq, bq, Wk, bk, Wa, ba, pre, starts, pts4, 0);
        attn_fallback<<<dim3(BDIM * NDIM / 4), dim3(256), 0, stream>>>(
            anchor, neighbor, Wd, bd, pre, out);
    }
}